// Round 8
// baseline (1426.130 us; speedup 1.0000x reference)
//
#include <hip/hip_runtime.h>

typedef __attribute__((ext_vector_type(8))) short short8;
typedef __attribute__((ext_vector_type(4))) short short4v;
typedef __attribute__((ext_vector_type(4))) float f32x4;

#define DEV __device__ __forceinline__

constexpr int T_LEN  = 2048;
constexpr int BATCH  = 32;
constexpr int F_IN   = 64;
constexpr int H_DIM  = 1024;
constexpr int HQ     = 256;
constexpr int KC     = 8;                // timesteps per chunk
constexpr int NCHUNK = T_LEN / KC;       // 256
constexpr int SROWS  = NCHUNK * BATCH;   // 8192 state rows
constexpr int JT     = 8;                // correction taps (W^1..W^8)
constexpr int BLK    = BATCH * H_DIM;    // elems per chunk-block (32x1024)

DEV unsigned short f2bf(float f) {
  union { float f; unsigned u; } v; v.f = f;
  return (unsigned short)((v.u + 0x7fffu + ((v.u >> 16) & 1u)) >> 16);
}
DEV float bf2f(unsigned short s) {
  union { unsigned u; float f; } v; v.u = ((unsigned)s) << 16;
  return v.f;
}

DEV void gload16(const unsigned short* src, unsigned short* ldsDst) {
  __builtin_amdgcn_global_load_lds(
      (const __attribute__((address_space(1))) void*)src,
      (__attribute__((address_space(3))) void*)ldsDst, 16, 0, 0);
}

// Build W_uh as W^T (row-major [n][k] -> Bstack block 0) and W row-major.
__global__ void build_wuh(const float* __restrict__ cr, const float* __restrict__ ci,
                          const float* __restrict__ cj, const float* __restrict__ ck,
                          unsigned short* __restrict__ WT, unsigned short* __restrict__ Wrow) {
  int id = blockIdx.x * 256 + threadIdx.x;   // id = n*1024 + k
  int n = id >> 10, k = id & 1023;
  int q = n >> 8, b = n & 255, p = k >> 8, a = k & 255;
  const float* comps[4] = {cr, ci, cj, ck};
  const int   csel[16] = {0,1,2,3, 1,0,3,2, 2,3,0,1, 3,2,1,0};
  const float csgn[16] = {1.f,-1.f,-1.f,-1.f, 1.f,1.f,-1.f,1.f,
                          1.f,1.f,1.f,-1.f, 1.f,-1.f,1.f,1.f};
  float v = csgn[q*4+p] * comps[csel[q*4+p]][a*HQ + b];
  unsigned short bv = f2bf(v);
  WT[(size_t)n * 1024 + k] = bv;
  Wrow[(size_t)k * 1024 + n] = bv;
}

// Build W_wx^T (bf16, [n=1024][k=64]).
__global__ void build_wwx(const float* __restrict__ cr, const float* __restrict__ ci,
                          const float* __restrict__ cj, const float* __restrict__ ck,
                          unsigned short* __restrict__ WT) {
  int id = blockIdx.x * 256 + threadIdx.x;   // id = n*64 + k
  int n = id >> 6, k = id & 63;
  int q = n >> 8, b = n & 255, p = k >> 4, a = k & 15;
  const float* comps[4] = {cr, ci, cj, ck};
  const int   csel[16] = {0,1,2,3, 1,0,3,2, 2,3,0,1, 3,2,1,0};
  const float csgn[16] = {1.f,-1.f,-1.f,-1.f, 1.f,1.f,-1.f,1.f,
                          1.f,1.f,1.f,-1.f, 1.f,-1.f,1.f,1.f};
  float v = csgn[q*4+p] * comps[csel[q*4+p]][a*HQ + b];
  WT[(size_t)n * 64 + k] = f2bf(v);
}

__global__ void build_bias(const float* __restrict__ a, const float* __restrict__ b,
                           float* __restrict__ o) {
  int i = blockIdx.x * 256 + threadIdx.x;
  if (i < H_DIM) o[i] = a[i] + b[i];
}

// Gather fp32 rows (optionally strided chunk mapping) -> contiguous bf16 rows.
__global__ void gather_bf16(unsigned short* __restrict__ dst, const float* __restrict__ src,
                            int mapStride, int jidx) {
  int r = blockIdx.x, tid = threadIdx.x;
  int g = mapStride ? ((r >> 5) * mapStride + jidx * BATCH + (r & 31)) : r;
  const float4* s = (const float4*)(src + (size_t)g * H_DIM);
  float4 v = s[tid];
  short4v o;
  o[0] = (short)f2bf(v.x); o[1] = (short)f2bf(v.y);
  o[2] = (short)f2bf(v.z); o[3] = (short)f2bf(v.w);
  *(short4v*)(dst + (size_t)r * H_DIM + tid * 4) = o;
}

__global__ void copy_hlast(float* __restrict__ out) {
  int b = blockIdx.x, tid = threadIdx.x;
  const float4* s = (const float4*)(out + ((size_t)(T_LEN - 1) * BATCH + b) * H_DIM);
  float4* d = (float4*)(out + (size_t)T_LEN * BATCH * H_DIM + (size_t)b * H_DIM);
  d[tid] = s[tid];
}

// C = A * Bt^T. A fp32 (cast to bf16, reg-staged) or bf16 (global_load_lds);
// Bt = [N][K] bf16 (global_load_lds). LINEAR LDS [rows][32], double-buffered,
// ONE raw s_barrier + vmcnt(0) per K-tile (T3-minimum 2-phase): stage(next)
// issued BEFORE compute(cur), so HBM latency hides under ds_read+MFMA.
// Epilogue semantics identical to round 4 (see comments there).
template<bool AF32, int BM, int BN>
__launch_bounds__(256)
__global__ void gemm3(const void* __restrict__ Ap, int lda,
                      const unsigned short* __restrict__ Bt,
                      int M, int N, int K,
                      float* __restrict__ outF,
                      const float* __restrict__ addF,
                      const float* __restrict__ bias,
                      unsigned short* __restrict__ stateOut,
                      const unsigned short* __restrict__ addBF,
                      unsigned short* __restrict__ stateOutT,
                      int mapStride, int jidx, int nsplit) {
  constexpr int TM = BM / 2, TN = BN / 2;    // 2x2 waves
  constexpr int FM = TM / 16, FN = TN / 16;
  __shared__ __align__(16) unsigned short Al[2][BM * 32];
  __shared__ __align__(16) unsigned short Bl[2][BN * 32];

  const int tid = threadIdx.x;
  const int lane = tid & 63, w = tid >> 6;

  // XCD-aware bijective block swizzle (T1, m204). All our grids have nwg%8==0.
  const int gx = gridDim.x;
  const int nwg = gx * gridDim.y;
  int lin = blockIdx.y * gx + blockIdx.x;
  int swz = lin;
  if ((nwg & 7) == 0 && nwg >= 16) swz = (lin & 7) * (nwg >> 3) + (lin >> 3);
  const int bm0 = (swz % gx) * BM, bn0 = (swz / gx) * BN;

  const int wm = (w >> 1) * TM, wn = (w & 1) * TN;
  const int lr = lane & 15, lk = (lane >> 4) * 8;

  f32x4 acc[FM][FN];
#pragma unroll
  for (int i = 0; i < FM; ++i)
#pragma unroll
    for (int j = 0; j < FN; ++j)
#pragma unroll
      for (int q = 0; q < 4; ++q) acc[i][j][q] = 0.f;

  auto stage = [&](int buf, int kt) {
    if constexpr (AF32) {
#pragma unroll
      for (int ch = 0; ch < BM / 64; ++ch) {
        int c = ch * 256 + tid;
        int row = c >> 2, kp = (c & 3) * 8;
        int gr = bm0 + row;
        short8 v;
#pragma unroll
        for (int e = 0; e < 8; ++e) v[e] = 0;
        if (gr < M) {
          const float* a = (const float*)Ap + (size_t)gr * lda + kt + kp;
          float4 x0 = *(const float4*)a;
          float4 x1 = *(const float4*)(a + 4);
          v[0] = (short)f2bf(x0.x); v[1] = (short)f2bf(x0.y);
          v[2] = (short)f2bf(x0.z); v[3] = (short)f2bf(x0.w);
          v[4] = (short)f2bf(x1.x); v[5] = (short)f2bf(x1.y);
          v[6] = (short)f2bf(x1.z); v[7] = (short)f2bf(x1.w);
        }
        *(short8*)&Al[buf][c * 8] = v;
      }
    } else {
#pragma unroll
      for (int ch = 0; ch < BM / 64; ++ch) {
        int c = ch * 256 + tid;
        int row = c >> 2, kp = (c & 3) * 8;
        int gr = bm0 + row;
        if (gr >= M) gr = M - 1;   // clamp: safe load, output masked later
        gload16((const unsigned short*)Ap + (size_t)gr * lda + kt + kp, &Al[buf][c * 8]);
      }
    }
#pragma unroll
    for (int ch = 0; ch < BN / 64; ++ch) {
      int c = ch * 256 + tid;
      int row = c >> 2, kp = (c & 3) * 8;
      gload16(Bt + (size_t)(bn0 + row) * K + kt + kp, &Bl[buf][c * 8]);
    }
  };

  auto compute = [&](int buf) {
    short8 af[FM], bfr[FN];
#pragma unroll
    for (int i = 0; i < FM; ++i)
      af[i] = *(const short8*)&Al[buf][(wm + i * 16 + lr) * 32 + lk];
#pragma unroll
    for (int j = 0; j < FN; ++j)
      bfr[j] = *(const short8*)&Bl[buf][(wn + j * 16 + lr) * 32 + lk];
    asm volatile("s_waitcnt lgkmcnt(0)" ::: "memory");
    __builtin_amdgcn_sched_barrier(0);
#pragma unroll
    for (int i = 0; i < FM; ++i)
#pragma unroll
      for (int j = 0; j < FN; ++j)
        acc[i][j] = __builtin_amdgcn_mfma_f32_16x16x32_bf16(af[i], bfr[j], acc[i][j], 0, 0, 0);
  };

  // prologue: stage tile 0, full drain (vm for gload_lds, lgkm for AF32 ds_write)
  stage(0, 0);
  asm volatile("s_waitcnt vmcnt(0) lgkmcnt(0)" ::: "memory");
  __builtin_amdgcn_s_barrier();
  asm volatile("" ::: "memory");
  __builtin_amdgcn_sched_barrier(0);

  int cur = 0;
  for (int kt = 32; kt < K; kt += 32) {
    stage(cur ^ 1, kt);          // issue next-tile loads FIRST
    compute(cur);                // ds_read + MFMA hide the load latency
    asm volatile("s_waitcnt vmcnt(0)" ::: "memory");
    __builtin_amdgcn_s_barrier();
    asm volatile("" ::: "memory");
    __builtin_amdgcn_sched_barrier(0);
    cur ^= 1;
  }
  compute(cur);

  // epilogue (identical to round 4)
#pragma unroll
  for (int i = 0; i < FM; ++i) {
    const int r0 = bm0 + wm + i * 16 + (lane >> 4) * 4;
#pragma unroll
    for (int j = 0; j < FN; ++j) {
      const int n = bn0 + wn + j * 16 + (lane & 15);
      short4v tv;
#pragma unroll
      for (int q = 0; q < 4; ++q) {
        int r = r0 + q;
        if (r >= M) continue;
        float v = acc[i][j][q];
        if (bias) v += bias[n];
        if (addBF) v += bf2f(addBF[(size_t)r * N + n]);
        int g, col;
        if (nsplit) { g = (r >> 5) * mapStride + (n >> 10) * BATCH + (r & 31); col = n & 1023; }
        else { g = mapStride ? ((r >> 5) * mapStride + jidx * BATCH + (r & 31)) : r; col = n; }
        if (addF) v += addF[(size_t)g * H_DIM + col];
        if (outF) outF[(size_t)g * H_DIM + col] = v;
        if (stateOut) stateOut[(size_t)r * N + n] = f2bf(v);
        tv[q] = (short)f2bf(v);
      }
      if (stateOutT && r0 < M)
        *(short4v*)(stateOutT + (size_t)n * M + r0) = tv;
    }
  }
}

extern "C" void kernel_launch(void* const* d_in, const int* in_sizes, int n_in,
                              void* d_out, int out_size, void* d_ws, size_t ws_size,
                              hipStream_t stream) {
  const float* x   = (const float*)d_in[0];
  const float* h0  = (const float*)d_in[1];
  const float* wxr = (const float*)d_in[2];
  const float* wxi = (const float*)d_in[3];
  const float* wxj = (const float*)d_in[4];
  const float* wxk = (const float*)d_in[5];
  const float* wxb = (const float*)d_in[6];
  const float* uhr = (const float*)d_in[7];
  const float* uhi = (const float*)d_in[8];
  const float* uhj = (const float*)d_in[9];
  const float* uhk = (const float*)d_in[10];
  const float* uhb = (const float*)d_in[11];
  float* out = (float*)d_out;

  constexpr size_t HH = (size_t)H_DIM * H_DIM;   // 1M elems
  char* ws = (char*)d_ws;
  size_t off = 0;
  auto take = [&](size_t bytes) { void* p = ws + off; off += (bytes + 255) & ~(size_t)255; return p; };
  unsigned short* Bstack = (unsigned short*)take(JT * HH * 2);       // (W^1..W^8)^T, 16 MB
  unsigned short* Wrow   = (unsigned short*)take(HH * 2);
  unsigned short* WwxT   = (unsigned short*)take((size_t)H_DIM * F_IN * 2);
  float*          bias   = (float*)take(H_DIM * 4);
  unsigned short* P2row  = (unsigned short*)take(HH * 2);
  unsigned short* P34row = (unsigned short*)take(2 * HH * 2);        // [1024][2048]
  unsigned short* P58row = (unsigned short*)take(4 * HH * 2);        // [1024][4096]
  unsigned short* P16T   = (unsigned short*)take(HH * 2);
  // Eext: 259 chunk-blocks. Eext[i] = E[i-3]; E[m]=Lend_m (m>=0), E[-1]=h0, E[<-1]=0.
  unsigned short* Eext   = (unsigned short*)take((size_t)(NCHUNK + 3) * BLK * 2);
  unsigned short* S      = (unsigned short*)take((size_t)SROWS * H_DIM * 2);
  unsigned short* Sa     = (unsigned short*)take((size_t)SROWS * H_DIM * 2);
  unsigned short* Sb     = (unsigned short*)take((size_t)SROWS * H_DIM * 2);
  if (off > ws_size) return;  // workspace too small; fail visibly

  build_wuh<<<dim3(HH / 256), 256, 0, stream>>>(uhr, uhi, uhj, uhk, Bstack, Wrow);
  build_wwx<<<dim3((H_DIM * F_IN) / 256), 256, 0, stream>>>(wxr, wxi, wxj, wxk, WwxT);
  build_bias<<<dim3(4), 256, 0, stream>>>(wxb, uhb, bias);

  // U = x @ W_wx + (wx_b + uh_b) -> out fp32, row t*32+b
  gemm3<true, 128, 128><<<dim3(T_LEN * BATCH / 128, H_DIM / 128), 256, 0, stream>>>(
      x, F_IN, WwxT, T_LEN * BATCH, H_DIM, F_IN,
      out, nullptr, bias, nullptr, nullptr, nullptr, 0, 0, 0);

  // Matrix powers (log-doubling); Bstack block m-1 = (W^m)^T.
  gemm3<false, 64, 128><<<dim3(16, 8), 256, 0, stream>>>(        // P2 = W@W
      Wrow, 1024, Bstack, 1024, 1024, 1024,
      nullptr, nullptr, nullptr, P2row, nullptr, Bstack + 1 * HH, 0, 0, 0);
  gemm3<false, 64, 128><<<dim3(16, 16), 256, 0, stream>>>(       // [P3,P4] = P2@[P1,P2]
      P2row, 1024, Bstack, 1024, 2048, 1024,
      nullptr, nullptr, nullptr, P34row, nullptr, Bstack + 2 * HH, 0, 0, 0);
  gemm3<false, 64, 128><<<dim3(16, 32), 256, 0, stream>>>(       // [P5..P8] = P4@[P1..P4]
      P34row + 1024, 2048, Bstack, 1024, 4096, 1024,
      nullptr, nullptr, nullptr, P58row, nullptr, Bstack + 4 * HH, 0, 0, 0);
  gemm3<false, 64, 128><<<dim3(16, 8), 256, 0, stream>>>(        // P16 = P8@P8
      P58row + 3 * 1024, 4096, Bstack + 7 * HH, 1024, 1024, 1024,
      nullptr, nullptr, nullptr, nullptr, nullptr, P16T, 0, 0, 0);

  // Pass A: chunk-local scans, zero init. L_{c,0} = U (already in out).
  gather_bf16<<<dim3(SROWS), 256, 0, stream>>>(Sa, out, KC * BATCH, 0);
  hipMemsetAsync(Eext, 0, 2 * (size_t)BLK * 2, stream);            // E[-3], E[-2] = 0
  gather_bf16<<<dim3(BATCH), 256, 0, stream>>>(Eext + 2 * (size_t)BLK, h0, 0, 0); // E[-1]=h0
  gather_bf16<<<dim3(BATCH), 256, 0, stream>>>(S, h0, 0, 0);       // s_0 = h0

  unsigned short* cur = Sa; unsigned short* nxt = Sb;
  for (int j = 1; j < KC; ++j) {
    unsigned short* so = (j == KC - 1) ? (Eext + 3 * (size_t)BLK) : nxt;  // Lend_c -> Eext[c+3]
    gemm3<false, 128, 128><<<dim3(SROWS / 128, H_DIM / 128), 256, 0, stream>>>(
        cur, 1024, Bstack, SROWS, H_DIM, H_DIM,
        out, out, nullptr, so, nullptr, nullptr, KC * BATCH, j, 0);
    unsigned short* t = cur; cur = nxt; nxt = t;
  }

  // S-fix (3-tap): S[c] = E[c-1] + E[c-2]@W^8 + E[c-3]@W^16, c = 1..255
  gemm3<false, 128, 128><<<dim3(SROWS / 128, H_DIM / 128), 256, 0, stream>>>(
      Eext + 2 * (size_t)BLK, 1024, Bstack + 7 * HH, SROWS - BATCH, H_DIM, H_DIM,
      nullptr, nullptr, nullptr, S + (size_t)BLK,
      Eext + 3 * (size_t)BLK, nullptr, 0, 0, 0);
  gemm3<false, 128, 128><<<dim3(SROWS / 128, H_DIM / 128), 256, 0, stream>>>(
      Eext + 1 * (size_t)BLK, 1024, P16T, SROWS - BATCH, H_DIM, H_DIM,
      nullptr, nullptr, nullptr, S + (size_t)BLK,
      S + (size_t)BLK, nullptr, 0, 0, 0);

  // Corrections: out[c*8+jm] += S[c] @ W^{jm+1}, all (c,jm) in one GEMM, N = 8*1024
  gemm3<false, 128, 128><<<dim3(SROWS / 128, JT * H_DIM / 128), 256, 0, stream>>>(
      S, 1024, Bstack, SROWS, JT * H_DIM, H_DIM,
      out, out, nullptr, nullptr, nullptr, nullptr, KC * BATCH, 0, 1);

  copy_hlast<<<dim3(BATCH), 256, 0, stream>>>(out);
}

// Round 9
// 1175.771 us; speedup vs baseline: 1.2129x; 1.2129x over previous
//
#include <hip/hip_runtime.h>

typedef __attribute__((ext_vector_type(8))) short short8;
typedef __attribute__((ext_vector_type(4))) short short4v;
typedef __attribute__((ext_vector_type(4))) float f32x4;

#define DEV __device__ __forceinline__

constexpr int T_LEN  = 2048;
constexpr int BATCH  = 32;
constexpr int F_IN   = 64;
constexpr int H_DIM  = 1024;
constexpr int HQ     = 256;
constexpr int KC     = 8;                // timesteps per chunk
constexpr int NCHUNK = T_LEN / KC;       // 256
constexpr int SROWS  = NCHUNK * BATCH;   // 8192 state rows
constexpr int JT     = 8;                // correction taps (W^1..W^8)
constexpr int BLK    = BATCH * H_DIM;    // elems per chunk-block (32x1024)

DEV unsigned short f2bf(float f) {
  union { float f; unsigned u; } v; v.f = f;
  return (unsigned short)((v.u + 0x7fffu + ((v.u >> 16) & 1u)) >> 16);
}
DEV float bf2f(unsigned short s) {
  union { unsigned u; float f; } v; v.u = ((unsigned)s) << 16;
  return v.f;
}

DEV void gload16(const unsigned short* src, unsigned short* ldsDst) {
  __builtin_amdgcn_global_load_lds(
      (const __attribute__((address_space(1))) void*)src,
      (__attribute__((address_space(3))) void*)ldsDst, 16, 0, 0);
}

// Build W_uh as W^T (row-major [n][k] -> Bstack block 0) and W row-major.
__global__ void build_wuh(const float* __restrict__ cr, const float* __restrict__ ci,
                          const float* __restrict__ cj, const float* __restrict__ ck,
                          unsigned short* __restrict__ WT, unsigned short* __restrict__ Wrow) {
  int id = blockIdx.x * 256 + threadIdx.x;   // id = n*1024 + k
  int n = id >> 10, k = id & 1023;
  int q = n >> 8, b = n & 255, p = k >> 8, a = k & 255;
  const float* comps[4] = {cr, ci, cj, ck};
  const int   csel[16] = {0,1,2,3, 1,0,3,2, 2,3,0,1, 3,2,1,0};
  const float csgn[16] = {1.f,-1.f,-1.f,-1.f, 1.f,1.f,-1.f,1.f,
                          1.f,1.f,1.f,-1.f, 1.f,-1.f,1.f,1.f};
  float v = csgn[q*4+p] * comps[csel[q*4+p]][a*HQ + b];
  unsigned short bv = f2bf(v);
  WT[(size_t)n * 1024 + k] = bv;
  Wrow[(size_t)k * 1024 + n] = bv;
}

// Build W_wx^T (bf16, [n=1024][k=64]).
__global__ void build_wwx(const float* __restrict__ cr, const float* __restrict__ ci,
                          const float* __restrict__ cj, const float* __restrict__ ck,
                          unsigned short* __restrict__ WT) {
  int id = blockIdx.x * 256 + threadIdx.x;   // id = n*64 + k
  int n = id >> 6, k = id & 63;
  int q = n >> 8, b = n & 255, p = k >> 4, a = k & 15;
  const float* comps[4] = {cr, ci, cj, ck};
  const int   csel[16] = {0,1,2,3, 1,0,3,2, 2,3,0,1, 3,2,1,0};
  const float csgn[16] = {1.f,-1.f,-1.f,-1.f, 1.f,1.f,-1.f,1.f,
                          1.f,1.f,1.f,-1.f, 1.f,-1.f,1.f,1.f};
  float v = csgn[q*4+p] * comps[csel[q*4+p]][a*HQ + b];
  WT[(size_t)n * 64 + k] = f2bf(v);
}

__global__ void build_bias(const float* __restrict__ a, const float* __restrict__ b,
                           float* __restrict__ o) {
  int i = blockIdx.x * 256 + threadIdx.x;
  if (i < H_DIM) o[i] = a[i] + b[i];
}

// Gather fp32 rows (optionally strided chunk mapping) -> contiguous bf16 rows.
__global__ void gather_bf16(unsigned short* __restrict__ dst, const float* __restrict__ src,
                            int mapStride, int jidx) {
  int r = blockIdx.x, tid = threadIdx.x;
  int g = mapStride ? ((r >> 5) * mapStride + jidx * BATCH + (r & 31)) : r;
  const float4* s = (const float4*)(src + (size_t)g * H_DIM);
  float4 v = s[tid];
  short4v o;
  o[0] = (short)f2bf(v.x); o[1] = (short)f2bf(v.y);
  o[2] = (short)f2bf(v.z); o[3] = (short)f2bf(v.w);
  *(short4v*)(dst + (size_t)r * H_DIM + tid * 4) = o;
}

__global__ void copy_hlast(float* __restrict__ out) {
  int b = blockIdx.x, tid = threadIdx.x;
  const float4* s = (const float4*)(out + ((size_t)(T_LEN - 1) * BATCH + b) * H_DIM);
  float4* d = (float4*)(out + (size_t)T_LEN * BATCH * H_DIM + (size_t)b * H_DIM);
  d[tid] = s[tid];
}

// ---------------- r4-proven general GEMM engine (gemm2), unchanged ----------------
template<bool AF32, int BM, int BN>
__launch_bounds__(256)
__global__ void gemm2(const void* __restrict__ Ap, int lda,
                      const unsigned short* __restrict__ Bt,
                      int M, int N, int K,
                      float* __restrict__ outF,
                      const float* __restrict__ addF,
                      const float* __restrict__ bias,
                      unsigned short* __restrict__ stateOut,
                      const unsigned short* __restrict__ addBF,
                      unsigned short* __restrict__ stateOutT,
                      int mapStride, int jidx, int nsplit) {
  constexpr int TM = BM / 2, TN = BN / 2;    // 2x2 waves
  constexpr int FM = TM / 16, FN = TN / 16;
  __shared__ __align__(16) unsigned short Al[BM * 32];
  __shared__ __align__(16) unsigned short Bl[BN * 32];

  const int tid = threadIdx.x;
  const int lane = tid & 63, w = tid >> 6;
  const int bm0 = blockIdx.x * BM, bn0 = blockIdx.y * BN;
  const int wm = (w >> 1) * TM, wn = (w & 1) * TN;
  const int lr = lane & 15, lk = (lane >> 4) * 8;

  f32x4 acc[FM][FN];
#pragma unroll
  for (int i = 0; i < FM; ++i)
#pragma unroll
    for (int j = 0; j < FN; ++j)
#pragma unroll
      for (int q = 0; q < 4; ++q) acc[i][j][q] = 0.f;

  for (int kt = 0; kt < K; kt += 32) {
    if constexpr (AF32) {
#pragma unroll
      for (int ch = 0; ch < BM / 64; ++ch) {
        int c = ch * 256 + tid;
        int row = c >> 2, kp = (c & 3) * 8;
        int gr = bm0 + row;
        short8 v;
#pragma unroll
        for (int e = 0; e < 8; ++e) v[e] = 0;
        if (gr < M) {
          const float* a = (const float*)Ap + (size_t)gr * lda + kt + kp;
          float4 x0 = *(const float4*)a;
          float4 x1 = *(const float4*)(a + 4);
          v[0] = (short)f2bf(x0.x); v[1] = (short)f2bf(x0.y);
          v[2] = (short)f2bf(x0.z); v[3] = (short)f2bf(x0.w);
          v[4] = (short)f2bf(x1.x); v[5] = (short)f2bf(x1.y);
          v[6] = (short)f2bf(x1.z); v[7] = (short)f2bf(x1.w);
        }
        *(short8*)&Al[c * 8] = v;
      }
    } else {
#pragma unroll
      for (int ch = 0; ch < BM / 64; ++ch) {
        int c = ch * 256 + tid;
        int row = c >> 2, kp = (c & 3) * 8;
        int gr = bm0 + row;
        if (gr >= M) gr = M - 1;   // clamp: safe load, output masked later
        const unsigned short* src = (const unsigned short*)Ap + (size_t)gr * lda + kt + kp;
        gload16(src, &Al[c * 8]);
      }
    }
#pragma unroll
    for (int ch = 0; ch < BN / 64; ++ch) {
      int c = ch * 256 + tid;
      int row = c >> 2, kp = (c & 3) * 8;
      const unsigned short* src = Bt + (size_t)(bn0 + row) * K + kt + kp;
      gload16(src, &Bl[c * 8]);
    }
    __syncthreads();
    short8 af[FM], bfr[FN];
#pragma unroll
    for (int i = 0; i < FM; ++i) af[i] = *(const short8*)&Al[(wm + i * 16 + lr) * 32 + lk];
#pragma unroll
    for (int j = 0; j < FN; ++j) bfr[j] = *(const short8*)&Bl[(wn + j * 16 + lr) * 32 + lk];
#pragma unroll
    for (int i = 0; i < FM; ++i)
#pragma unroll
      for (int j = 0; j < FN; ++j)
        acc[i][j] = __builtin_amdgcn_mfma_f32_16x16x32_bf16(af[i], bfr[j], acc[i][j], 0, 0, 0);
    __syncthreads();
  }

#pragma unroll
  for (int i = 0; i < FM; ++i) {
    const int r0 = bm0 + wm + i * 16 + (lane >> 4) * 4;
#pragma unroll
    for (int j = 0; j < FN; ++j) {
      const int n = bn0 + wn + j * 16 + (lane & 15);
      short4v tv;
#pragma unroll
      for (int q = 0; q < 4; ++q) {
        int r = r0 + q;
        if (r >= M) continue;
        float v = acc[i][j][q];
        if (bias) v += bias[n];
        if (addBF) v += bf2f(addBF[(size_t)r * N + n]);
        int g, col;
        if (nsplit) { g = (r >> 5) * mapStride + (n >> 10) * BATCH + (r & 31); col = n & 1023; }
        else { g = mapStride ? ((r >> 5) * mapStride + jidx * BATCH + (r & 31)) : r; col = n; }
        if (addF) v += addF[(size_t)g * H_DIM + col];
        if (outF) outF[(size_t)g * H_DIM + col] = v;
        if (stateOut) stateOut[(size_t)r * N + n] = f2bf(v);
        tv[q] = (short)f2bf(v);
      }
      if (stateOutT && r0 < M)
        *(short4v*)(stateOutT + (size_t)n * M + r0) = tv;
    }
  }
}

// ------------- 256x256 / BK=64 phase-structured GEMM (corr only) -------------
// 8 waves (2M x 4N), per-wave 128x64. LDS 128 KiB: [dbuf][half][128][64] x {A,B}.
// T2 XOR-swizzle (col16 ^= row&7): linear gload_lds dest + inverse-swizzled
// per-lane global SOURCE + swizzled ds_read (both-sides rule).
// T4 counted vmcnt: stage tile t+2 after read-done barrier, then vmcnt(8)
// (forces tile t+1 landed, keeps t+2's 8 loads in flight). Never vmcnt(0)
// until the tail. Epilogue: fp32 RMW via the chunk mapping (nsplit form).
__launch_bounds__(512)
__global__ void gemm256(const unsigned short* __restrict__ A,
                        const unsigned short* __restrict__ Bt,
                        float* __restrict__ outF,
                        const float* __restrict__ addF,
                        int K, int mapStride) {
  __shared__ __align__(16) unsigned short As[2][2][128][64];
  __shared__ __align__(16) unsigned short Bs[2][2][128][64];

  const int tid = threadIdx.x;
  const int lane = tid & 63, w = tid >> 6;
  const int wm = w >> 2, wn = w & 3;          // 2x4 wave grid
  const int lr = lane & 15, hi = lane >> 4;
  const int bm0 = blockIdx.x * 256, bn0 = blockIdx.y * 256;

  f32x4 acc[8][4];
#pragma unroll
  for (int i = 0; i < 8; ++i)
#pragma unroll
    for (int j = 0; j < 4; ++j)
#pragma unroll
      for (int q = 0; q < 4; ++q) acc[i][j][q] = 0.f;

  auto stageTile = [&](int b, int t) {
    const int kt = t * 64;
#pragma unroll
    for (int h = 0; h < 2; ++h)
#pragma unroll
      for (int li = 0; li < 2; ++li) {
        int s = li * 512 + tid;              // 0..1023 slots of 16B
        int row = s >> 3, c16 = s & 7;
        gload16(A + (size_t)(bm0 + h * 128 + row) * K + kt + ((c16 ^ (row & 7)) << 3),
                &As[b][h][row][c16 * 8]);
      }
#pragma unroll
    for (int h = 0; h < 2; ++h)
#pragma unroll
      for (int li = 0; li < 2; ++li) {
        int s = li * 512 + tid;
        int row = s >> 3, c16 = s & 7;
        gload16(Bt + (size_t)(bn0 + h * 128 + row) * K + kt + ((c16 ^ (row & 7)) << 3),
                &Bs[b][h][row][c16 * 8]);
      }
  };

  auto phase = [&](int b, int mh, int nh) {
    short8 af[4][2], bw[2][2];
#pragma unroll
    for (int mf = 0; mf < 4; ++mf)
#pragma unroll
      for (int kk = 0; kk < 2; ++kk) {
        int rl = mh * 64 + mf * 16 + lr;
        int c16 = ((kk << 2) + hi) ^ (lr & 7);
        af[mf][kk] = *(const short8*)&As[b][wm][rl][c16 * 8];
      }
#pragma unroll
    for (int nf = 0; nf < 2; ++nf)
#pragma unroll
      for (int kk = 0; kk < 2; ++kk) {
        int rn = (wn & 1) * 64 + (nh * 2 + nf) * 16 + lr;
        int c16 = ((kk << 2) + hi) ^ (lr & 7);
        bw[nf][kk] = *(const short8*)&Bs[b][wn >> 1][rn][c16 * 8];
      }
    asm volatile("s_waitcnt lgkmcnt(0)" ::: "memory");
    __builtin_amdgcn_sched_barrier(0);
    __builtin_amdgcn_s_setprio(1);
#pragma unroll
    for (int mf = 0; mf < 4; ++mf)
#pragma unroll
      for (int nf = 0; nf < 2; ++nf)
#pragma unroll
        for (int kk = 0; kk < 2; ++kk)
          acc[mh * 4 + mf][nh * 2 + nf] = __builtin_amdgcn_mfma_f32_16x16x32_bf16(
              af[mf][kk], bw[nf][kk], acc[mh * 4 + mf][nh * 2 + nf], 0, 0, 0);
    __builtin_amdgcn_s_setprio(0);
    __builtin_amdgcn_sched_barrier(0);
  };

  const int NT = K / 64;                       // 16
  stageTile(0, 0);
  stageTile(1, 1);
  asm volatile("s_waitcnt vmcnt(8)" ::: "memory");   // tile 0 landed; tile 1 in flight
  __builtin_amdgcn_s_barrier();
  asm volatile("" ::: "memory");
  __builtin_amdgcn_sched_barrier(0);

  for (int t = 0; t < NT; ++t) {
    const int b = t & 1;
    phase(b, 0, 0); phase(b, 0, 1); phase(b, 1, 0); phase(b, 1, 1);
    // all waves done reading buf b before it is overwritten
    asm volatile("" ::: "memory");
    __builtin_amdgcn_s_barrier();
    asm volatile("" ::: "memory");
    if (t + 2 < NT) {
      stageTile(b, t + 2);
      asm volatile("s_waitcnt vmcnt(8)" ::: "memory"); // t+1 landed; t+2 stays in flight
    } else {
      asm volatile("s_waitcnt vmcnt(0)" ::: "memory"); // tail drain
    }
    __builtin_amdgcn_s_barrier();
    asm volatile("" ::: "memory");
    __builtin_amdgcn_sched_barrier(0);
  }

  // epilogue: fp32 RMW through chunk mapping (nsplit form)
#pragma unroll
  for (int i = 0; i < 8; ++i) {
    const int r0 = bm0 + wm * 128 + i * 16 + hi * 4;
#pragma unroll
    for (int j = 0; j < 4; ++j) {
      const int n = bn0 + wn * 64 + j * 16 + lr;
      const int col = n & 1023, jm = n >> 10;
#pragma unroll
      for (int q = 0; q < 4; ++q) {
        int r = r0 + q;
        int g = (r >> 5) * mapStride + jm * BATCH + (r & 31);
        float v = acc[i][j][q] + addF[(size_t)g * H_DIM + col];
        outF[(size_t)g * H_DIM + col] = v;
      }
    }
  }
}

extern "C" void kernel_launch(void* const* d_in, const int* in_sizes, int n_in,
                              void* d_out, int out_size, void* d_ws, size_t ws_size,
                              hipStream_t stream) {
  const float* x   = (const float*)d_in[0];
  const float* h0  = (const float*)d_in[1];
  const float* wxr = (const float*)d_in[2];
  const float* wxi = (const float*)d_in[3];
  const float* wxj = (const float*)d_in[4];
  const float* wxk = (const float*)d_in[5];
  const float* wxb = (const float*)d_in[6];
  const float* uhr = (const float*)d_in[7];
  const float* uhi = (const float*)d_in[8];
  const float* uhj = (const float*)d_in[9];
  const float* uhk = (const float*)d_in[10];
  const float* uhb = (const float*)d_in[11];
  float* out = (float*)d_out;

  constexpr size_t HH = (size_t)H_DIM * H_DIM;   // 1M elems
  char* ws = (char*)d_ws;
  size_t off = 0;
  auto take = [&](size_t bytes) { void* p = ws + off; off += (bytes + 255) & ~(size_t)255; return p; };
  unsigned short* Bstack = (unsigned short*)take(JT * HH * 2);       // (W^1..W^8)^T, 16 MB
  unsigned short* Wrow   = (unsigned short*)take(HH * 2);
  unsigned short* WwxT   = (unsigned short*)take((size_t)H_DIM * F_IN * 2);
  float*          bias   = (float*)take(H_DIM * 4);
  unsigned short* P2row  = (unsigned short*)take(HH * 2);
  unsigned short* P34row = (unsigned short*)take(2 * HH * 2);        // [1024][2048]
  unsigned short* P58row = (unsigned short*)take(4 * HH * 2);        // [1024][4096]
  unsigned short* P16T   = (unsigned short*)take(HH * 2);
  // Eext: 259 chunk-blocks. Eext[i] = E[i-3]; E[m]=Lend_m (m>=0), E[-1]=h0, E[<-1]=0.
  unsigned short* Eext   = (unsigned short*)take((size_t)(NCHUNK + 3) * BLK * 2);
  unsigned short* S      = (unsigned short*)take((size_t)SROWS * H_DIM * 2);
  unsigned short* Sa     = (unsigned short*)take((size_t)SROWS * H_DIM * 2);
  unsigned short* Sb     = (unsigned short*)take((size_t)SROWS * H_DIM * 2);
  if (off > ws_size) return;  // workspace too small; fail visibly

  build_wuh<<<dim3(HH / 256), 256, 0, stream>>>(uhr, uhi, uhj, uhk, Bstack, Wrow);
  build_wwx<<<dim3((H_DIM * F_IN) / 256), 256, 0, stream>>>(wxr, wxi, wxj, wxk, WwxT);
  build_bias<<<dim3(4), 256, 0, stream>>>(wxb, uhb, bias);

  // U = x @ W_wx + (wx_b + uh_b) -> out fp32, row t*32+b
  gemm2<true, 128, 128><<<dim3(T_LEN * BATCH / 128, H_DIM / 128), 256, 0, stream>>>(
      x, F_IN, WwxT, T_LEN * BATCH, H_DIM, F_IN,
      out, nullptr, bias, nullptr, nullptr, nullptr, 0, 0, 0);

  // Matrix powers (log-doubling); Bstack block m-1 = (W^m)^T.
  gemm2<false, 64, 128><<<dim3(16, 8), 256, 0, stream>>>(        // P2 = W@W
      Wrow, 1024, Bstack, 1024, 1024, 1024,
      nullptr, nullptr, nullptr, P2row, nullptr, Bstack + 1 * HH, 0, 0, 0);
  gemm2<false, 64, 128><<<dim3(16, 16), 256, 0, stream>>>(       // [P3,P4] = P2@[P1,P2]
      P2row, 1024, Bstack, 1024, 2048, 1024,
      nullptr, nullptr, nullptr, P34row, nullptr, Bstack + 2 * HH, 0, 0, 0);
  gemm2<false, 64, 128><<<dim3(16, 32), 256, 0, stream>>>(       // [P5..P8] = P4@[P1..P4]
      P34row + 1024, 2048, Bstack, 1024, 4096, 1024,
      nullptr, nullptr, nullptr, P58row, nullptr, Bstack + 4 * HH, 0, 0, 0);
  gemm2<false, 64, 128><<<dim3(16, 8), 256, 0, stream>>>(        // P16 = P8@P8
      P58row + 3 * 1024, 4096, Bstack + 7 * HH, 1024, 1024, 1024,
      nullptr, nullptr, nullptr, nullptr, nullptr, P16T, 0, 0, 0);

  // Pass A: chunk-local scans, zero init. L_{c,0} = U (already in out).
  gather_bf16<<<dim3(SROWS), 256, 0, stream>>>(Sa, out, KC * BATCH, 0);
  hipMemsetAsync(Eext, 0, 2 * (size_t)BLK * 2, stream);            // E[-3], E[-2] = 0
  gather_bf16<<<dim3(BATCH), 256, 0, stream>>>(Eext + 2 * (size_t)BLK, h0, 0, 0); // E[-1]=h0
  gather_bf16<<<dim3(BATCH), 256, 0, stream>>>(S, h0, 0, 0);       // s_0 = h0

  unsigned short* cur = Sa; unsigned short* nxt = Sb;
  for (int j = 1; j < KC; ++j) {
    unsigned short* so = (j == KC - 1) ? (Eext + 3 * (size_t)BLK) : nxt;  // Lend_c -> Eext[c+3]
    gemm2<false, 128, 128><<<dim3(SROWS / 128, H_DIM / 128), 256, 0, stream>>>(
        cur, 1024, Bstack, SROWS, H_DIM, H_DIM,
        out, out, nullptr, so, nullptr, nullptr, KC * BATCH, j, 0);
    unsigned short* t = cur; cur = nxt; nxt = t;
  }

  // S-fix (3-tap): S[c] = E[c-1] + E[c-2]@W^8 + E[c-3]@W^16, c = 1..255
  gemm2<false, 128, 128><<<dim3(SROWS / 128, H_DIM / 128), 256, 0, stream>>>(
      Eext + 2 * (size_t)BLK, 1024, Bstack + 7 * HH, SROWS - BATCH, H_DIM, H_DIM,
      nullptr, nullptr, nullptr, S + (size_t)BLK,
      Eext + 3 * (size_t)BLK, nullptr, 0, 0, 0);
  gemm2<false, 128, 128><<<dim3(SROWS / 128, H_DIM / 128), 256, 0, stream>>>(
      Eext + 1 * (size_t)BLK, 1024, P16T, SROWS - BATCH, H_DIM, H_DIM,
      nullptr, nullptr, nullptr, S + (size_t)BLK,
      S + (size_t)BLK, nullptr, 0, 0, 0);

  // Corrections: out[c*8+jm] += S[c] @ W^{jm+1}, all (c,jm) in one GEMM, N = 8*1024
  gemm256<<<dim3(SROWS / 256, JT * H_DIM / 256), 512, 0, stream>>>(
      S, Bstack, out, out, H_DIM, KC * BATCH);

  copy_hlast<<<dim3(BATCH), 256, 0, stream>>>(out);
}

// Round 10
// 863.728 us; speedup vs baseline: 1.6511x; 1.3613x over previous
//
#include <hip/hip_runtime.h>

typedef __attribute__((ext_vector_type(8))) short short8;
typedef __attribute__((ext_vector_type(4))) short short4v;
typedef __attribute__((ext_vector_type(4))) float f32x4;

#define DEV __device__ __forceinline__

constexpr int T_LEN  = 2048;
constexpr int BATCH  = 32;
constexpr int F_IN   = 64;
constexpr int H_DIM  = 1024;
constexpr int HQ     = 256;
constexpr int KC     = 8;                // timesteps per chunk
constexpr int NCHUNK = T_LEN / KC;       // 256
constexpr int SROWS  = NCHUNK * BATCH;   // 8192 state rows
constexpr int JT     = 8;                // correction taps (W^1..W^8)
constexpr int BLK    = BATCH * H_DIM;    // elems per chunk-block (32x1024)
constexpr int ULW    = JT * H_DIM;       // UL row width = 8192

DEV unsigned short f2bf(float f) {
  union { float f; unsigned u; } v; v.f = f;
  return (unsigned short)((v.u + 0x7fffu + ((v.u >> 16) & 1u)) >> 16);
}
DEV float bf2f(unsigned short s) {
  union { unsigned u; float f; } v; v.u = ((unsigned)s) << 16;
  return v.f;
}

DEV void gload16(const unsigned short* src, unsigned short* ldsDst) {
  __builtin_amdgcn_global_load_lds(
      (const __attribute__((address_space(1))) void*)src,
      (__attribute__((address_space(3))) void*)ldsDst, 16, 0, 0);
}

// Build W_uh as W^T (row-major [n][k] -> Bstack block 0) and W row-major.
__global__ void build_wuh(const float* __restrict__ cr, const float* __restrict__ ci,
                          const float* __restrict__ cj, const float* __restrict__ ck,
                          unsigned short* __restrict__ WT, unsigned short* __restrict__ Wrow) {
  int id = blockIdx.x * 256 + threadIdx.x;   // id = n*1024 + k
  int n = id >> 10, k = id & 1023;
  int q = n >> 8, b = n & 255, p = k >> 8, a = k & 255;
  const float* comps[4] = {cr, ci, cj, ck};
  const int   csel[16] = {0,1,2,3, 1,0,3,2, 2,3,0,1, 3,2,1,0};
  const float csgn[16] = {1.f,-1.f,-1.f,-1.f, 1.f,1.f,-1.f,1.f,
                          1.f,1.f,1.f,-1.f, 1.f,-1.f,1.f,1.f};
  float v = csgn[q*4+p] * comps[csel[q*4+p]][a*HQ + b];
  unsigned short bv = f2bf(v);
  WT[(size_t)n * 1024 + k] = bv;
  Wrow[(size_t)k * 1024 + n] = bv;
}

// Build W_wx^T (bf16, [n=1024][k=64]).
__global__ void build_wwx(const float* __restrict__ cr, const float* __restrict__ ci,
                          const float* __restrict__ cj, const float* __restrict__ ck,
                          unsigned short* __restrict__ WT) {
  int id = blockIdx.x * 256 + threadIdx.x;   // id = n*64 + k
  int n = id >> 6, k = id & 63;
  int q = n >> 8, b = n & 255, p = k >> 4, a = k & 15;
  const float* comps[4] = {cr, ci, cj, ck};
  const int   csel[16] = {0,1,2,3, 1,0,3,2, 2,3,0,1, 3,2,1,0};
  const float csgn[16] = {1.f,-1.f,-1.f,-1.f, 1.f,1.f,-1.f,1.f,
                          1.f,1.f,1.f,-1.f, 1.f,-1.f,1.f,1.f};
  float v = csgn[q*4+p] * comps[csel[q*4+p]][a*HQ + b];
  WT[(size_t)n * 64 + k] = f2bf(v);
}

__global__ void build_bias(const float* __restrict__ a, const float* __restrict__ b,
                           float* __restrict__ o) {
  int i = blockIdx.x * 256 + threadIdx.x;
  if (i < H_DIM) o[i] = a[i] + b[i];
}

// Gather fp32 rows -> contiguous bf16 rows (h0 staging).
__global__ void gather_bf16(unsigned short* __restrict__ dst, const float* __restrict__ src) {
  int r = blockIdx.x, tid = threadIdx.x;
  const float4* s = (const float4*)(src + (size_t)r * H_DIM);
  float4 v = s[tid];
  short4v o;
  o[0] = (short)f2bf(v.x); o[1] = (short)f2bf(v.y);
  o[2] = (short)f2bf(v.z); o[3] = (short)f2bf(v.w);
  *(short4v*)(dst + (size_t)r * H_DIM + tid * 4) = o;
}

__global__ void copy_hlast(float* __restrict__ out) {
  int b = blockIdx.x, tid = threadIdx.x;
  const float4* s = (const float4*)(out + ((size_t)(T_LEN - 1) * BATCH + b) * H_DIM);
  float4* d = (float4*)(out + (size_t)T_LEN * BATCH * H_DIM + (size_t)b * H_DIM);
  d[tid] = s[tid];
}

// ---------------- r4-proven GEMM engine core; bf16-only epilogue ----------------
// C = A * Bt^T. A fp32 (reg-staged cast) or bf16 (global_load_lds); Bt=[N][K] bf16.
// Epilogue (all optional): bias[n]; addBF bf16 at [r*strideBF + n];
//   stateOut bf16: smode 0 -> [r*strideS + n];
//                  smode 1 (qsplit, gemm_u) -> [((r>>8)*32+(r&31))*strideS
//                                               + ((r>>5)&7)*H_DIM + n];
//   stateOutC bf16 contiguous [r*N + n]; stateOutT bf16 transposed [n*M + r].
template<bool AF32, int BM, int BN>
__launch_bounds__(256)
__global__ void gemm2(const void* __restrict__ Ap, int lda,
                      const unsigned short* __restrict__ Bt,
                      int M, int N, int K,
                      const float* __restrict__ bias,
                      const unsigned short* __restrict__ addBF, int strideBF,
                      unsigned short* __restrict__ stateOut, int strideS, int smode,
                      unsigned short* __restrict__ stateOutC,
                      unsigned short* __restrict__ stateOutT) {
  constexpr int TM = BM / 2, TN = BN / 2;    // 2x2 waves
  constexpr int FM = TM / 16, FN = TN / 16;
  __shared__ __align__(16) unsigned short Al[BM * 32];
  __shared__ __align__(16) unsigned short Bl[BN * 32];

  const int tid = threadIdx.x;
  const int lane = tid & 63, w = tid >> 6;
  const int bm0 = blockIdx.x * BM, bn0 = blockIdx.y * BN;
  const int wm = (w >> 1) * TM, wn = (w & 1) * TN;
  const int lr = lane & 15, lk = (lane >> 4) * 8;

  f32x4 acc[FM][FN];
#pragma unroll
  for (int i = 0; i < FM; ++i)
#pragma unroll
    for (int j = 0; j < FN; ++j)
#pragma unroll
      for (int q = 0; q < 4; ++q) acc[i][j][q] = 0.f;

  for (int kt = 0; kt < K; kt += 32) {
    if constexpr (AF32) {
#pragma unroll
      for (int ch = 0; ch < BM / 64; ++ch) {
        int c = ch * 256 + tid;
        int row = c >> 2, kp = (c & 3) * 8;
        int gr = bm0 + row;
        short8 v;
#pragma unroll
        for (int e = 0; e < 8; ++e) v[e] = 0;
        if (gr < M) {
          const float* a = (const float*)Ap + (size_t)gr * lda + kt + kp;
          float4 x0 = *(const float4*)a;
          float4 x1 = *(const float4*)(a + 4);
          v[0] = (short)f2bf(x0.x); v[1] = (short)f2bf(x0.y);
          v[2] = (short)f2bf(x0.z); v[3] = (short)f2bf(x0.w);
          v[4] = (short)f2bf(x1.x); v[5] = (short)f2bf(x1.y);
          v[6] = (short)f2bf(x1.z); v[7] = (short)f2bf(x1.w);
        }
        *(short8*)&Al[c * 8] = v;
      }
    } else {
#pragma unroll
      for (int ch = 0; ch < BM / 64; ++ch) {
        int c = ch * 256 + tid;
        int row = c >> 2, kp = (c & 3) * 8;
        int gr = bm0 + row;
        if (gr >= M) gr = M - 1;   // clamp: safe load, output masked later
        const unsigned short* src = (const unsigned short*)Ap + (size_t)gr * lda + kt + kp;
        gload16(src, &Al[c * 8]);
      }
    }
#pragma unroll
    for (int ch = 0; ch < BN / 64; ++ch) {
      int c = ch * 256 + tid;
      int row = c >> 2, kp = (c & 3) * 8;
      const unsigned short* src = Bt + (size_t)(bn0 + row) * K + kt + kp;
      gload16(src, &Bl[c * 8]);
    }
    __syncthreads();
    short8 af[FM], bfr[FN];
#pragma unroll
    for (int i = 0; i < FM; ++i) af[i] = *(const short8*)&Al[(wm + i * 16 + lr) * 32 + lk];
#pragma unroll
    for (int j = 0; j < FN; ++j) bfr[j] = *(const short8*)&Bl[(wn + j * 16 + lr) * 32 + lk];
#pragma unroll
    for (int i = 0; i < FM; ++i)
#pragma unroll
      for (int j = 0; j < FN; ++j)
        acc[i][j] = __builtin_amdgcn_mfma_f32_16x16x32_bf16(af[i], bfr[j], acc[i][j], 0, 0, 0);
    __syncthreads();
  }

#pragma unroll
  for (int i = 0; i < FM; ++i) {
    const int r0 = bm0 + wm + i * 16 + (lane >> 4) * 4;
#pragma unroll
    for (int j = 0; j < FN; ++j) {
      const int n = bn0 + wn + j * 16 + (lane & 15);
      short4v tv;
#pragma unroll
      for (int q = 0; q < 4; ++q) {
        int r = r0 + q;
        if (r >= M) continue;
        float v = acc[i][j][q];
        if (bias) v += bias[n];
        if (addBF) v += bf2f(addBF[(size_t)r * strideBF + n]);
        unsigned short bv = f2bf(v);
        if (stateOut) {
          if (smode == 0) {
            stateOut[(size_t)r * strideS + n] = bv;
          } else {
            int srow = (r >> 8) * 32 + (r & 31);
            int scol = ((r >> 5) & 7) * H_DIM + n;
            stateOut[(size_t)srow * strideS + scol] = bv;
          }
        }
        if (stateOutC) stateOutC[(size_t)r * N + n] = bv;
        tv[q] = (short)bv;
      }
      if (stateOutT && r0 < M)
        *(short4v*)(stateOutT + (size_t)n * M + r0) = tv;
    }
  }
}

// ------------- 256x256 / BK=64 phase-structured GEMM (corr only) -------------
// Schedule identical to round 9 (verified: 0 bank conflicts). Epilogue changed:
// addend is bf16 UL (contiguous [r][n], n = j*1024+col), output is the single
// fp32 write of out via the chunk mapping. No fp32 read anywhere.
__launch_bounds__(512)
__global__ void gemm256(const unsigned short* __restrict__ A,
                        const unsigned short* __restrict__ Bt,
                        const unsigned short* __restrict__ addBF,
                        float* __restrict__ outF,
                        int K, int mapStride) {
  __shared__ __align__(16) unsigned short As[2][2][128][64];
  __shared__ __align__(16) unsigned short Bs[2][2][128][64];

  const int tid = threadIdx.x;
  const int lane = tid & 63, w = tid >> 6;
  const int wm = w >> 2, wn = w & 3;          // 2x4 wave grid
  const int lr = lane & 15, hi = lane >> 4;
  const int bm0 = blockIdx.x * 256, bn0 = blockIdx.y * 256;

  f32x4 acc[8][4];
#pragma unroll
  for (int i = 0; i < 8; ++i)
#pragma unroll
    for (int j = 0; j < 4; ++j)
#pragma unroll
      for (int q = 0; q < 4; ++q) acc[i][j][q] = 0.f;

  auto stageTile = [&](int b, int t) {
    const int kt = t * 64;
#pragma unroll
    for (int h = 0; h < 2; ++h)
#pragma unroll
      for (int li = 0; li < 2; ++li) {
        int s = li * 512 + tid;              // 0..1023 slots of 16B
        int row = s >> 3, c16 = s & 7;
        gload16(A + (size_t)(bm0 + h * 128 + row) * K + kt + ((c16 ^ (row & 7)) << 3),
                &As[b][h][row][c16 * 8]);
      }
#pragma unroll
    for (int h = 0; h < 2; ++h)
#pragma unroll
      for (int li = 0; li < 2; ++li) {
        int s = li * 512 + tid;
        int row = s >> 3, c16 = s & 7;
        gload16(Bt + (size_t)(bn0 + h * 128 + row) * K + kt + ((c16 ^ (row & 7)) << 3),
                &Bs[b][h][row][c16 * 8]);
      }
  };

  auto phase = [&](int b, int mh, int nh) {
    short8 af[4][2], bw[2][2];
#pragma unroll
    for (int mf = 0; mf < 4; ++mf)
#pragma unroll
      for (int kk = 0; kk < 2; ++kk) {
        int rl = mh * 64 + mf * 16 + lr;
        int c16 = ((kk << 2) + hi) ^ (lr & 7);
        af[mf][kk] = *(const short8*)&As[b][wm][rl][c16 * 8];
      }
#pragma unroll
    for (int nf = 0; nf < 2; ++nf)
#pragma unroll
      for (int kk = 0; kk < 2; ++kk) {
        int rn = (wn & 1) * 64 + (nh * 2 + nf) * 16 + lr;
        int c16 = ((kk << 2) + hi) ^ (lr & 7);
        bw[nf][kk] = *(const short8*)&Bs[b][wn >> 1][rn][c16 * 8];
      }
    asm volatile("s_waitcnt lgkmcnt(0)" ::: "memory");
    __builtin_amdgcn_sched_barrier(0);
    __builtin_amdgcn_s_setprio(1);
#pragma unroll
    for (int mf = 0; mf < 4; ++mf)
#pragma unroll
      for (int nf = 0; nf < 2; ++nf)
#pragma unroll
        for (int kk = 0; kk < 2; ++kk)
          acc[mh * 4 + mf][nh * 2 + nf] = __builtin_amdgcn_mfma_f32_16x16x32_bf16(
              af[mf][kk], bw[nf][kk], acc[mh * 4 + mf][nh * 2 + nf], 0, 0, 0);
    __builtin_amdgcn_s_setprio(0);
    __builtin_amdgcn_sched_barrier(0);
  };

  const int NT = K / 64;                       // 16
  stageTile(0, 0);
  stageTile(1, 1);
  asm volatile("s_waitcnt vmcnt(8)" ::: "memory");   // tile 0 landed; tile 1 in flight
  __builtin_amdgcn_s_barrier();
  asm volatile("" ::: "memory");
  __builtin_amdgcn_sched_barrier(0);

  for (int t = 0; t < NT; ++t) {
    const int b = t & 1;
    phase(b, 0, 0); phase(b, 0, 1); phase(b, 1, 0); phase(b, 1, 1);
    asm volatile("" ::: "memory");
    __builtin_amdgcn_s_barrier();
    asm volatile("" ::: "memory");
    if (t + 2 < NT) {
      stageTile(b, t + 2);
      asm volatile("s_waitcnt vmcnt(8)" ::: "memory"); // t+1 landed; t+2 stays in flight
    } else {
      asm volatile("s_waitcnt vmcnt(0)" ::: "memory"); // tail drain
    }
    __builtin_amdgcn_s_barrier();
    asm volatile("" ::: "memory");
    __builtin_amdgcn_sched_barrier(0);
  }

  // epilogue: out = acc + UL (bf16), single fp32 write through chunk mapping
#pragma unroll
  for (int i = 0; i < 8; ++i) {
    const int r0 = bm0 + wm * 128 + i * 16 + hi * 4;
#pragma unroll
    for (int j = 0; j < 4; ++j) {
      const int n = bn0 + wn * 64 + j * 16 + lr;
      const int col = n & 1023, jm = n >> 10;
#pragma unroll
      for (int q = 0; q < 4; ++q) {
        int r = r0 + q;
        float v = acc[i][j][q] + bf2f(addBF[(size_t)r * ULW + n]);
        int g = (r >> 5) * mapStride + jm * BATCH + (r & 31);
        outF[(size_t)g * H_DIM + col] = v;
      }
    }
  }
}

extern "C" void kernel_launch(void* const* d_in, const int* in_sizes, int n_in,
                              void* d_out, int out_size, void* d_ws, size_t ws_size,
                              hipStream_t stream) {
  const float* x   = (const float*)d_in[0];
  const float* h0  = (const float*)d_in[1];
  const float* wxr = (const float*)d_in[2];
  const float* wxi = (const float*)d_in[3];
  const float* wxj = (const float*)d_in[4];
  const float* wxk = (const float*)d_in[5];
  const float* wxb = (const float*)d_in[6];
  const float* uhr = (const float*)d_in[7];
  const float* uhi = (const float*)d_in[8];
  const float* uhj = (const float*)d_in[9];
  const float* uhk = (const float*)d_in[10];
  const float* uhb = (const float*)d_in[11];
  float* out = (float*)d_out;

  constexpr size_t HH = (size_t)H_DIM * H_DIM;   // 1M elems
  char* ws = (char*)d_ws;
  size_t off = 0;
  auto take = [&](size_t bytes) { void* p = ws + off; off += (bytes + 255) & ~(size_t)255; return p; };
  unsigned short* Bstack = (unsigned short*)take(JT * HH * 2);       // (W^1..W^8)^T, 16 MB
  unsigned short* Wrow   = (unsigned short*)take(HH * 2);
  unsigned short* WwxT   = (unsigned short*)take((size_t)H_DIM * F_IN * 2);
  float*          bias   = (float*)take(H_DIM * 4);
  unsigned short* P2row  = (unsigned short*)take(HH * 2);
  unsigned short* P34row = (unsigned short*)take(2 * HH * 2);        // [1024][2048]
  unsigned short* P58row = (unsigned short*)take(4 * HH * 2);        // [1024][4096]
  unsigned short* P16T   = (unsigned short*)take(HH * 2);
  // Eext: 259 chunk-blocks. Eext[i] = E[i-3]; E[m]=Lend_m (m>=0), E[-1]=h0, E[<-1]=0.
  unsigned short* Eext   = (unsigned short*)take((size_t)(NCHUNK + 3) * BLK * 2);
  unsigned short* S      = (unsigned short*)take((size_t)SROWS * H_DIM * 2);
  // UL: bf16 [c*32+b][j*1024+col]; U written by gemm_u, overwritten by L in pass A.
  unsigned short* UL     = (unsigned short*)take((size_t)SROWS * ULW * 2);  // 128 MB
  if (off > ws_size) return;  // workspace too small; fail visibly

  build_wuh<<<dim3(HH / 256), 256, 0, stream>>>(uhr, uhi, uhj, uhk, Bstack, Wrow);
  build_wwx<<<dim3((H_DIM * F_IN) / 256), 256, 0, stream>>>(wxr, wxi, wxj, wxk, WwxT);
  build_bias<<<dim3(4), 256, 0, stream>>>(wxb, uhb, bias);

  // U = x @ W_wx + (wx_b + uh_b) -> UL bf16, qsplit layout (NO fp32 out write)
  gemm2<true, 128, 128><<<dim3(T_LEN * BATCH / 128, H_DIM / 128), 256, 0, stream>>>(
      x, F_IN, WwxT, T_LEN * BATCH, H_DIM, F_IN,
      bias, nullptr, 0, UL, ULW, 1, nullptr, nullptr);

  // Matrix powers (log-doubling); Bstack block m-1 = (W^m)^T.
  gemm2<false, 64, 128><<<dim3(16, 8), 256, 0, stream>>>(        // P2 = W@W
      Wrow, 1024, Bstack, 1024, 1024, 1024,
      nullptr, nullptr, 0, P2row, 1024, 0, nullptr, Bstack + 1 * HH);
  gemm2<false, 64, 128><<<dim3(16, 16), 256, 0, stream>>>(       // [P3,P4] = P2@[P1,P2]
      P2row, 1024, Bstack, 1024, 2048, 1024,
      nullptr, nullptr, 0, P34row, 2048, 0, nullptr, Bstack + 2 * HH);
  gemm2<false, 64, 128><<<dim3(16, 32), 256, 0, stream>>>(       // [P5..P8] = P4@[P1..P4]
      P34row + 1024, 2048, Bstack, 1024, 4096, 1024,
      nullptr, nullptr, 0, P58row, 4096, 0, nullptr, Bstack + 4 * HH);
  gemm2<false, 64, 128><<<dim3(16, 8), 256, 0, stream>>>(        // P16 = P8@P8
      P58row + 3 * 1024, 4096, Bstack + 7 * HH, 1024, 1024, 1024,
      nullptr, nullptr, 0, nullptr, 0, 0, nullptr, P16T);

  // Guard blocks + s_0
  hipMemsetAsync(Eext, 0, 2 * (size_t)BLK * 2, stream);             // E[-3], E[-2] = 0
  gather_bf16<<<dim3(BATCH), 256, 0, stream>>>(Eext + 2 * (size_t)BLK, h0); // E[-1]=h0
  gather_bf16<<<dim3(BATCH), 256, 0, stream>>>(S, h0);              // s_0 = h0

  // Pass A: L_j = L_{j-1}@W + U_j, all in UL col-blocks (bf16 only).
  for (int j = 1; j < KC; ++j) {
    unsigned short* soC = (j == KC - 1) ? (Eext + 3 * (size_t)BLK) : nullptr; // Lend->Eext
    gemm2<false, 128, 128><<<dim3(SROWS / 128, H_DIM / 128), 256, 0, stream>>>(
        UL + (size_t)(j - 1) * H_DIM, ULW, Bstack, SROWS, H_DIM, H_DIM,
        nullptr, UL + (size_t)j * H_DIM, ULW,
        UL + (size_t)j * H_DIM, ULW, 0, soC, nullptr);
  }

  // S-fix (3-tap): S[c] = E[c-1] + E[c-2]@W^8 + E[c-3]@W^16, c = 1..255
  gemm2<false, 128, 128><<<dim3(SROWS / 128, H_DIM / 128), 256, 0, stream>>>(
      Eext + 2 * (size_t)BLK, 1024, Bstack + 7 * HH, SROWS - BATCH, H_DIM, H_DIM,
      nullptr, Eext + 3 * (size_t)BLK, 1024,
      S + (size_t)BLK, 1024, 0, nullptr, nullptr);
  gemm2<false, 128, 128><<<dim3(SROWS / 128, H_DIM / 128), 256, 0, stream>>>(
      Eext + 1 * (size_t)BLK, 1024, P16T, SROWS - BATCH, H_DIM, H_DIM,
      nullptr, S + (size_t)BLK, 1024,
      S + (size_t)BLK, 1024, 0, nullptr, nullptr);

  // Corrections + final assembly: out[c*8+jm] = UL[c][jm] + S[c] @ W^{jm+1}
  gemm256<<<dim3(SROWS / 256, ULW / 256), 512, 0, stream>>>(
      S, Bstack, UL, out, H_DIM, KC * BATCH);

  copy_hlast<<<dim3(BATCH), 256, 0, stream>>>(out);
}

// Round 11
// 811.284 us; speedup vs baseline: 1.7579x; 1.0646x over previous
//
#include <hip/hip_runtime.h>

typedef __attribute__((ext_vector_type(8))) short short8;
typedef __attribute__((ext_vector_type(4))) short short4v;
typedef __attribute__((ext_vector_type(4))) float f32x4;

#define DEV __device__ __forceinline__

constexpr int T_LEN  = 2048;
constexpr int BATCH  = 32;
constexpr int F_IN   = 64;
constexpr int H_DIM  = 1024;
constexpr int HQ     = 256;
constexpr int KC     = 8;                // timesteps per chunk
constexpr int NCHUNK = T_LEN / KC;       // 256
constexpr int SROWS  = NCHUNK * BATCH;   // 8192 state rows
constexpr int JT     = 8;                // correction taps (W^1..W^8)
constexpr int BLK    = BATCH * H_DIM;    // elems per chunk-block (32x1024)
constexpr int ULW    = JT * H_DIM;       // UL row width = 8192

DEV unsigned short f2bf(float f) {
  union { float f; unsigned u; } v; v.f = f;
  return (unsigned short)((v.u + 0x7fffu + ((v.u >> 16) & 1u)) >> 16);
}
DEV float bf2f(unsigned short s) {
  union { unsigned u; float f; } v; v.u = ((unsigned)s) << 16;
  return v.f;
}

DEV void gload16(const unsigned short* src, unsigned short* ldsDst) {
  __builtin_amdgcn_global_load_lds(
      (const __attribute__((address_space(1))) void*)src,
      (__attribute__((address_space(3))) void*)ldsDst, 16, 0, 0);
}

// Build W_uh as W^T (row-major [n][k] -> Bstack block 0) and W row-major.
__global__ void build_wuh(const float* __restrict__ cr, const float* __restrict__ ci,
                          const float* __restrict__ cj, const float* __restrict__ ck,
                          unsigned short* __restrict__ WT, unsigned short* __restrict__ Wrow) {
  int id = blockIdx.x * 256 + threadIdx.x;   // id = n*1024 + k
  int n = id >> 10, k = id & 1023;
  int q = n >> 8, b = n & 255, p = k >> 8, a = k & 255;
  const float* comps[4] = {cr, ci, cj, ck};
  const int   csel[16] = {0,1,2,3, 1,0,3,2, 2,3,0,1, 3,2,1,0};
  const float csgn[16] = {1.f,-1.f,-1.f,-1.f, 1.f,1.f,-1.f,1.f,
                          1.f,1.f,1.f,-1.f, 1.f,-1.f,1.f,1.f};
  float v = csgn[q*4+p] * comps[csel[q*4+p]][a*HQ + b];
  unsigned short bv = f2bf(v);
  WT[(size_t)n * 1024 + k] = bv;
  Wrow[(size_t)k * 1024 + n] = bv;
}

// Build W_wx^T (bf16, [n=1024][k=64]).
__global__ void build_wwx(const float* __restrict__ cr, const float* __restrict__ ci,
                          const float* __restrict__ cj, const float* __restrict__ ck,
                          unsigned short* __restrict__ WT) {
  int id = blockIdx.x * 256 + threadIdx.x;   // id = n*64 + k
  int n = id >> 6, k = id & 63;
  int q = n >> 8, b = n & 255, p = k >> 4, a = k & 15;
  const float* comps[4] = {cr, ci, cj, ck};
  const int   csel[16] = {0,1,2,3, 1,0,3,2, 2,3,0,1, 3,2,1,0};
  const float csgn[16] = {1.f,-1.f,-1.f,-1.f, 1.f,1.f,-1.f,1.f,
                          1.f,1.f,1.f,-1.f, 1.f,-1.f,1.f,1.f};
  float v = csgn[q*4+p] * comps[csel[q*4+p]][a*HQ + b];
  WT[(size_t)n * 64 + k] = f2bf(v);
}

__global__ void build_bias(const float* __restrict__ a, const float* __restrict__ b,
                           float* __restrict__ o) {
  int i = blockIdx.x * 256 + threadIdx.x;
  if (i < H_DIM) o[i] = a[i] + b[i];
}

// Gather fp32 rows -> contiguous bf16 rows (h0 staging).
__global__ void gather_bf16(unsigned short* __restrict__ dst, const float* __restrict__ src) {
  int r = blockIdx.x, tid = threadIdx.x;
  const float4* s = (const float4*)(src + (size_t)r * H_DIM);
  float4 v = s[tid];
  short4v o;
  o[0] = (short)f2bf(v.x); o[1] = (short)f2bf(v.y);
  o[2] = (short)f2bf(v.z); o[3] = (short)f2bf(v.w);
  *(short4v*)(dst + (size_t)r * H_DIM + tid * 4) = o;
}

__global__ void copy_hlast(float* __restrict__ out) {
  int b = blockIdx.x, tid = threadIdx.x;
  const float4* s = (const float4*)(out + ((size_t)(T_LEN - 1) * BATCH + b) * H_DIM);
  float4* d = (float4*)(out + (size_t)T_LEN * BATCH * H_DIM + (size_t)b * H_DIM);
  d[tid] = s[tid];
}

// ---------------- r4-proven GEMM engine (gemm_u + powers only) ----------------
template<bool AF32, int BM, int BN>
__launch_bounds__(256)
__global__ void gemm2(const void* __restrict__ Ap, int lda,
                      const unsigned short* __restrict__ Bt,
                      int M, int N, int K,
                      const float* __restrict__ bias,
                      const unsigned short* __restrict__ addBF, int strideBF,
                      unsigned short* __restrict__ stateOut, int strideS, int smode,
                      unsigned short* __restrict__ stateOutC,
                      unsigned short* __restrict__ stateOutT) {
  constexpr int TM = BM / 2, TN = BN / 2;    // 2x2 waves
  constexpr int FM = TM / 16, FN = TN / 16;
  __shared__ __align__(16) unsigned short Al[BM * 32];
  __shared__ __align__(16) unsigned short Bl[BN * 32];

  const int tid = threadIdx.x;
  const int lane = tid & 63, w = tid >> 6;
  const int bm0 = blockIdx.x * BM, bn0 = blockIdx.y * BN;
  const int wm = (w >> 1) * TM, wn = (w & 1) * TN;
  const int lr = lane & 15, lk = (lane >> 4) * 8;

  f32x4 acc[FM][FN];
#pragma unroll
  for (int i = 0; i < FM; ++i)
#pragma unroll
    for (int j = 0; j < FN; ++j)
#pragma unroll
      for (int q = 0; q < 4; ++q) acc[i][j][q] = 0.f;

  for (int kt = 0; kt < K; kt += 32) {
    if constexpr (AF32) {
#pragma unroll
      for (int ch = 0; ch < BM / 64; ++ch) {
        int c = ch * 256 + tid;
        int row = c >> 2, kp = (c & 3) * 8;
        int gr = bm0 + row;
        short8 v;
#pragma unroll
        for (int e = 0; e < 8; ++e) v[e] = 0;
        if (gr < M) {
          const float* a = (const float*)Ap + (size_t)gr * lda + kt + kp;
          float4 x0 = *(const float4*)a;
          float4 x1 = *(const float4*)(a + 4);
          v[0] = (short)f2bf(x0.x); v[1] = (short)f2bf(x0.y);
          v[2] = (short)f2bf(x0.z); v[3] = (short)f2bf(x0.w);
          v[4] = (short)f2bf(x1.x); v[5] = (short)f2bf(x1.y);
          v[6] = (short)f2bf(x1.z); v[7] = (short)f2bf(x1.w);
        }
        *(short8*)&Al[c * 8] = v;
      }
    } else {
#pragma unroll
      for (int ch = 0; ch < BM / 64; ++ch) {
        int c = ch * 256 + tid;
        int row = c >> 2, kp = (c & 3) * 8;
        int gr = bm0 + row;
        if (gr >= M) gr = M - 1;   // clamp: safe load, output masked later
        const unsigned short* src = (const unsigned short*)Ap + (size_t)gr * lda + kt + kp;
        gload16(src, &Al[c * 8]);
      }
    }
#pragma unroll
    for (int ch = 0; ch < BN / 64; ++ch) {
      int c = ch * 256 + tid;
      int row = c >> 2, kp = (c & 3) * 8;
      const unsigned short* src = Bt + (size_t)(bn0 + row) * K + kt + kp;
      gload16(src, &Bl[c * 8]);
    }
    __syncthreads();
    short8 af[FM], bfr[FN];
#pragma unroll
    for (int i = 0; i < FM; ++i) af[i] = *(const short8*)&Al[(wm + i * 16 + lr) * 32 + lk];
#pragma unroll
    for (int j = 0; j < FN; ++j) bfr[j] = *(const short8*)&Bl[(wn + j * 16 + lr) * 32 + lk];
#pragma unroll
    for (int i = 0; i < FM; ++i)
#pragma unroll
      for (int j = 0; j < FN; ++j)
        acc[i][j] = __builtin_amdgcn_mfma_f32_16x16x32_bf16(af[i], bfr[j], acc[i][j], 0, 0, 0);
    __syncthreads();
  }

#pragma unroll
  for (int i = 0; i < FM; ++i) {
    const int r0 = bm0 + wm + i * 16 + (lane >> 4) * 4;
#pragma unroll
    for (int j = 0; j < FN; ++j) {
      const int n = bn0 + wn + j * 16 + (lane & 15);
      short4v tv;
#pragma unroll
      for (int q = 0; q < 4; ++q) {
        int r = r0 + q;
        if (r >= M) continue;
        float v = acc[i][j][q];
        if (bias) v += bias[n];
        if (addBF) v += bf2f(addBF[(size_t)r * strideBF + n]);
        unsigned short bv = f2bf(v);
        if (stateOut) {
          if (smode == 0) {
            stateOut[(size_t)r * strideS + n] = bv;
          } else {
            int srow = (r >> 8) * 32 + (r & 31);
            int scol = ((r >> 5) & 7) * H_DIM + n;
            stateOut[(size_t)srow * strideS + scol] = bv;
          }
        }
        if (stateOutC) stateOutC[(size_t)r * N + n] = bv;
        tv[q] = (short)bv;
      }
      if (stateOutT && r0 < M)
        *(short4v*)(stateOutT + (size_t)n * M + r0) = tv;
    }
  }
}

// --------- 128x128 / BK=64 counted-vmcnt GEMM (pass A + S-fix) ---------
// Direct transplant of gemm256's verified schedule (0 bank conflicts, r9/r10)
// to 4 waves (2x2, 64x64/wave), LDS 64 KB -> 2 blocks/CU. Same T2 XOR-swizzle
// (linear gload dest + inverse-swizzled source + swizzled ds_read), same
// prologue {stage t0,t1; vmcnt(8)} and per-tile {phases; barrier; stage t+2;
// vmcnt(8); barrier} (8 gload16/tile/wave -> identical count arithmetic).
// C = A*Bt^T + addBF (bf16), written bf16 to stateOut (+optional stateOutC).
// M = gridDim.x*128 exactly (no masking).
__launch_bounds__(256)
__global__ void gemmA(const unsigned short* __restrict__ A, int lda,
                      const unsigned short* __restrict__ Bt, int K,
                      const unsigned short* __restrict__ addBF, int strideBF,
                      unsigned short* __restrict__ stateOut, int strideS,
                      unsigned short* __restrict__ stateOutC) {
  __shared__ __align__(16) unsigned short As[2][128][64];
  __shared__ __align__(16) unsigned short Bs[2][128][64];

  const int tid = threadIdx.x;
  const int lane = tid & 63, w = tid >> 6;
  const int wm = w >> 1, wn = w & 1;          // 2x2 wave grid
  const int lr = lane & 15, hi = lane >> 4;
  const int bm0 = blockIdx.x * 128, bn0 = blockIdx.y * 128;

  f32x4 acc[4][4];
#pragma unroll
  for (int i = 0; i < 4; ++i)
#pragma unroll
    for (int j = 0; j < 4; ++j)
#pragma unroll
      for (int q = 0; q < 4; ++q) acc[i][j][q] = 0.f;

  auto stageTile = [&](int b, int t) {
    const int kt = t * 64;
#pragma unroll
    for (int li = 0; li < 4; ++li) {
      int s = li * 256 + tid;                  // 0..1023 slots of 16B
      int row = s >> 3, c16 = s & 7;
      gload16(A + (size_t)(bm0 + row) * lda + kt + ((c16 ^ (row & 7)) << 3),
              &As[b][row][c16 * 8]);
    }
#pragma unroll
    for (int li = 0; li < 4; ++li) {
      int s = li * 256 + tid;
      int row = s >> 3, c16 = s & 7;
      gload16(Bt + (size_t)(bn0 + row) * K + kt + ((c16 ^ (row & 7)) << 3),
              &Bs[b][row][c16 * 8]);
    }
  };

  short8 af[4][2];
  auto phase = [&](int b, int nh, bool firstPhase) {
    if (firstPhase) {
#pragma unroll
      for (int mf = 0; mf < 4; ++mf)
#pragma unroll
        for (int kk = 0; kk < 2; ++kk) {
          int rl = wm * 64 + mf * 16 + lr;
          int c16 = ((kk << 2) + hi) ^ (lr & 7);
          af[mf][kk] = *(const short8*)&As[b][rl][c16 * 8];
        }
    }
    short8 bw[2][2];
#pragma unroll
    for (int nf = 0; nf < 2; ++nf)
#pragma unroll
      for (int kk = 0; kk < 2; ++kk) {
        int rn = wn * 64 + (nh * 2 + nf) * 16 + lr;
        int c16 = ((kk << 2) + hi) ^ (lr & 7);
        bw[nf][kk] = *(const short8*)&Bs[b][rn][c16 * 8];
      }
    asm volatile("s_waitcnt lgkmcnt(0)" ::: "memory");
    __builtin_amdgcn_sched_barrier(0);
    __builtin_amdgcn_s_setprio(1);
#pragma unroll
    for (int mf = 0; mf < 4; ++mf)
#pragma unroll
      for (int nf = 0; nf < 2; ++nf)
#pragma unroll
        for (int kk = 0; kk < 2; ++kk)
          acc[mf][nh * 2 + nf] = __builtin_amdgcn_mfma_f32_16x16x32_bf16(
              af[mf][kk], bw[nf][kk], acc[mf][nh * 2 + nf], 0, 0, 0);
    __builtin_amdgcn_s_setprio(0);
    __builtin_amdgcn_sched_barrier(0);
  };

  const int NT = K / 64;                       // 16
  stageTile(0, 0);
  stageTile(1, 1);
  asm volatile("s_waitcnt vmcnt(8)" ::: "memory");   // tile 0 landed; tile 1 in flight
  __builtin_amdgcn_s_barrier();
  asm volatile("" ::: "memory");
  __builtin_amdgcn_sched_barrier(0);

  for (int t = 0; t < NT; ++t) {
    const int b = t & 1;
    phase(b, 0, true); phase(b, 1, false);
    asm volatile("" ::: "memory");
    __builtin_amdgcn_s_barrier();              // all waves done reading buf b
    asm volatile("" ::: "memory");
    if (t + 2 < NT) {
      stageTile(b, t + 2);
      asm volatile("s_waitcnt vmcnt(8)" ::: "memory"); // t+1 landed; t+2 in flight
    } else {
      asm volatile("s_waitcnt vmcnt(0)" ::: "memory"); // tail drain
    }
    __builtin_amdgcn_s_barrier();
    asm volatile("" ::: "memory");
    __builtin_amdgcn_sched_barrier(0);
  }

  // epilogue: bf16 out = acc + addBF
#pragma unroll
  for (int mf = 0; mf < 4; ++mf) {
    const int r0 = bm0 + wm * 64 + mf * 16 + hi * 4;
#pragma unroll
    for (int nf = 0; nf < 4; ++nf) {
      const int n = bn0 + wn * 64 + nf * 16 + lr;
#pragma unroll
      for (int q = 0; q < 4; ++q) {
        int r = r0 + q;
        float v = acc[mf][nf][q];
        if (addBF) v += bf2f(addBF[(size_t)r * strideBF + n]);
        unsigned short bv = f2bf(v);
        stateOut[(size_t)r * strideS + n] = bv;
        if (stateOutC) stateOutC[(size_t)r * H_DIM + n] = bv;
      }
    }
  }
}

// ------------- 256x256 / BK=64 phase-structured GEMM (corr only) -------------
__launch_bounds__(512)
__global__ void gemm256(const unsigned short* __restrict__ A,
                        const unsigned short* __restrict__ Bt,
                        const unsigned short* __restrict__ addBF,
                        float* __restrict__ outF,
                        int K, int mapStride) {
  __shared__ __align__(16) unsigned short As[2][2][128][64];
  __shared__ __align__(16) unsigned short Bs[2][2][128][64];

  const int tid = threadIdx.x;
  const int lane = tid & 63, w = tid >> 6;
  const int wm = w >> 2, wn = w & 3;          // 2x4 wave grid
  const int lr = lane & 15, hi = lane >> 4;
  const int bm0 = blockIdx.x * 256, bn0 = blockIdx.y * 256;

  f32x4 acc[8][4];
#pragma unroll
  for (int i = 0; i < 8; ++i)
#pragma unroll
    for (int j = 0; j < 4; ++j)
#pragma unroll
      for (int q = 0; q < 4; ++q) acc[i][j][q] = 0.f;

  auto stageTile = [&](int b, int t) {
    const int kt = t * 64;
#pragma unroll
    for (int h = 0; h < 2; ++h)
#pragma unroll
      for (int li = 0; li < 2; ++li) {
        int s = li * 512 + tid;              // 0..1023 slots of 16B
        int row = s >> 3, c16 = s & 7;
        gload16(A + (size_t)(bm0 + h * 128 + row) * K + kt + ((c16 ^ (row & 7)) << 3),
                &As[b][h][row][c16 * 8]);
      }
#pragma unroll
    for (int h = 0; h < 2; ++h)
#pragma unroll
      for (int li = 0; li < 2; ++li) {
        int s = li * 512 + tid;
        int row = s >> 3, c16 = s & 7;
        gload16(Bt + (size_t)(bn0 + h * 128 + row) * K + kt + ((c16 ^ (row & 7)) << 3),
                &Bs[b][h][row][c16 * 8]);
      }
  };

  auto phase = [&](int b, int mh, int nh) {
    short8 af[4][2], bw[2][2];
#pragma unroll
    for (int mf = 0; mf < 4; ++mf)
#pragma unroll
      for (int kk = 0; kk < 2; ++kk) {
        int rl = mh * 64 + mf * 16 + lr;
        int c16 = ((kk << 2) + hi) ^ (lr & 7);
        af[mf][kk] = *(const short8*)&As[b][wm][rl][c16 * 8];
      }
#pragma unroll
    for (int nf = 0; nf < 2; ++nf)
#pragma unroll
      for (int kk = 0; kk < 2; ++kk) {
        int rn = (wn & 1) * 64 + (nh * 2 + nf) * 16 + lr;
        int c16 = ((kk << 2) + hi) ^ (lr & 7);
        bw[nf][kk] = *(const short8*)&Bs[b][wn >> 1][rn][c16 * 8];
      }
    asm volatile("s_waitcnt lgkmcnt(0)" ::: "memory");
    __builtin_amdgcn_sched_barrier(0);
    __builtin_amdgcn_s_setprio(1);
#pragma unroll
    for (int mf = 0; mf < 4; ++mf)
#pragma unroll
      for (int nf = 0; nf < 2; ++nf)
#pragma unroll
        for (int kk = 0; kk < 2; ++kk)
          acc[mh * 4 + mf][nh * 2 + nf] = __builtin_amdgcn_mfma_f32_16x16x32_bf16(
              af[mf][kk], bw[nf][kk], acc[mh * 4 + mf][nh * 2 + nf], 0, 0, 0);
    __builtin_amdgcn_s_setprio(0);
    __builtin_amdgcn_sched_barrier(0);
  };

  const int NT = K / 64;                       // 16
  stageTile(0, 0);
  stageTile(1, 1);
  asm volatile("s_waitcnt vmcnt(8)" ::: "memory");   // tile 0 landed; tile 1 in flight
  __builtin_amdgcn_s_barrier();
  asm volatile("" ::: "memory");
  __builtin_amdgcn_sched_barrier(0);

  for (int t = 0; t < NT; ++t) {
    const int b = t & 1;
    phase(b, 0, 0); phase(b, 0, 1); phase(b, 1, 0); phase(b, 1, 1);
    asm volatile("" ::: "memory");
    __builtin_amdgcn_s_barrier();
    asm volatile("" ::: "memory");
    if (t + 2 < NT) {
      stageTile(b, t + 2);
      asm volatile("s_waitcnt vmcnt(8)" ::: "memory"); // t+1 landed; t+2 stays in flight
    } else {
      asm volatile("s_waitcnt vmcnt(0)" ::: "memory"); // tail drain
    }
    __builtin_amdgcn_s_barrier();
    asm volatile("" ::: "memory");
    __builtin_amdgcn_sched_barrier(0);
  }

  // epilogue: out = acc + UL (bf16), single fp32 write through chunk mapping
#pragma unroll
  for (int i = 0; i < 8; ++i) {
    const int r0 = bm0 + wm * 128 + i * 16 + hi * 4;
#pragma unroll
    for (int j = 0; j < 4; ++j) {
      const int n = bn0 + wn * 64 + j * 16 + lr;
      const int col = n & 1023, jm = n >> 10;
#pragma unroll
      for (int q = 0; q < 4; ++q) {
        int r = r0 + q;
        float v = acc[i][j][q] + bf2f(addBF[(size_t)r * ULW + n]);
        int g = (r >> 5) * mapStride + jm * BATCH + (r & 31);
        outF[(size_t)g * H_DIM + col] = v;
      }
    }
  }
}

extern "C" void kernel_launch(void* const* d_in, const int* in_sizes, int n_in,
                              void* d_out, int out_size, void* d_ws, size_t ws_size,
                              hipStream_t stream) {
  const float* x   = (const float*)d_in[0];
  const float* h0  = (const float*)d_in[1];
  const float* wxr = (const float*)d_in[2];
  const float* wxi = (const float*)d_in[3];
  const float* wxj = (const float*)d_in[4];
  const float* wxk = (const float*)d_in[5];
  const float* wxb = (const float*)d_in[6];
  const float* uhr = (const float*)d_in[7];
  const float* uhi = (const float*)d_in[8];
  const float* uhj = (const float*)d_in[9];
  const float* uhk = (const float*)d_in[10];
  const float* uhb = (const float*)d_in[11];
  float* out = (float*)d_out;

  constexpr size_t HH = (size_t)H_DIM * H_DIM;   // 1M elems
  char* ws = (char*)d_ws;
  size_t off = 0;
  auto take = [&](size_t bytes) { void* p = ws + off; off += (bytes + 255) & ~(size_t)255; return p; };
  unsigned short* Bstack = (unsigned short*)take(JT * HH * 2);       // (W^1..W^8)^T, 16 MB
  unsigned short* Wrow   = (unsigned short*)take(HH * 2);
  unsigned short* WwxT   = (unsigned short*)take((size_t)H_DIM * F_IN * 2);
  float*          bias   = (float*)take(H_DIM * 4);
  unsigned short* P2row  = (unsigned short*)take(HH * 2);
  unsigned short* P34row = (unsigned short*)take(2 * HH * 2);        // [1024][2048]
  unsigned short* P58row = (unsigned short*)take(4 * HH * 2);        // [1024][4096]
  unsigned short* P16T   = (unsigned short*)take(HH * 2);
  // Eext: 259 chunk-blocks. Eext[i] = E[i-3]; E[m]=Lend_m (m>=0), E[-1]=h0, E[<-1]=0.
  unsigned short* Eext   = (unsigned short*)take((size_t)(NCHUNK + 3) * BLK * 2);
  // S padded +BATCH rows: unmasked M=8192 S-fix writes spill into padding.
  unsigned short* S      = (unsigned short*)take((size_t)(SROWS + BATCH) * H_DIM * 2);
  // UL: bf16 [c*32+b][j*1024+col]; U written by gemm_u, overwritten by L in pass A.
  unsigned short* UL     = (unsigned short*)take((size_t)SROWS * ULW * 2);  // 128 MB
  if (off > ws_size) return;  // workspace too small; fail visibly

  build_wuh<<<dim3(HH / 256), 256, 0, stream>>>(uhr, uhi, uhj, uhk, Bstack, Wrow);
  build_wwx<<<dim3((H_DIM * F_IN) / 256), 256, 0, stream>>>(wxr, wxi, wxj, wxk, WwxT);
  build_bias<<<dim3(4), 256, 0, stream>>>(wxb, uhb, bias);

  // U = x @ W_wx + (wx_b + uh_b) -> UL bf16, qsplit layout
  gemm2<true, 128, 128><<<dim3(T_LEN * BATCH / 128, H_DIM / 128), 256, 0, stream>>>(
      x, F_IN, WwxT, T_LEN * BATCH, H_DIM, F_IN,
      bias, nullptr, 0, UL, ULW, 1, nullptr, nullptr);

  // Matrix powers (log-doubling); Bstack block m-1 = (W^m)^T.
  gemm2<false, 64, 128><<<dim3(16, 8), 256, 0, stream>>>(        // P2 = W@W
      Wrow, 1024, Bstack, 1024, 1024, 1024,
      nullptr, nullptr, 0, P2row, 1024, 0, nullptr, Bstack + 1 * HH);
  gemm2<false, 64, 128><<<dim3(16, 16), 256, 0, stream>>>(       // [P3,P4] = P2@[P1,P2]
      P2row, 1024, Bstack, 1024, 2048, 1024,
      nullptr, nullptr, 0, P34row, 2048, 0, nullptr, Bstack + 2 * HH);
  gemm2<false, 64, 128><<<dim3(16, 32), 256, 0, stream>>>(       // [P5..P8] = P4@[P1..P4]
      P34row + 1024, 2048, Bstack, 1024, 4096, 1024,
      nullptr, nullptr, 0, P58row, 4096, 0, nullptr, Bstack + 4 * HH);
  gemm2<false, 64, 128><<<dim3(16, 8), 256, 0, stream>>>(        // P16 = P8@P8
      P58row + 3 * 1024, 4096, Bstack + 7 * HH, 1024, 1024, 1024,
      nullptr, nullptr, 0, nullptr, 0, 0, nullptr, P16T);

  // Guard blocks + s_0
  hipMemsetAsync(Eext, 0, 2 * (size_t)BLK * 2, stream);             // E[-3], E[-2] = 0
  gather_bf16<<<dim3(BATCH), 256, 0, stream>>>(Eext + 2 * (size_t)BLK, h0); // E[-1]=h0
  gather_bf16<<<dim3(BATCH), 256, 0, stream>>>(S, h0);              // s_0 = h0

  // Pass A: L_j = L_{j-1}@W + U_j, all in UL col-blocks (bf16 only, gemmA).
  for (int j = 1; j < KC; ++j) {
    unsigned short* soC = (j == KC - 1) ? (Eext + 3 * (size_t)BLK) : nullptr; // Lend->Eext
    gemmA<<<dim3(SROWS / 128, H_DIM / 128), 256, 0, stream>>>(
        UL + (size_t)(j - 1) * H_DIM, ULW, Bstack, H_DIM,
        UL + (size_t)j * H_DIM, ULW,
        UL + (size_t)j * H_DIM, ULW, soC);
  }

  // S-fix (3-tap, unmasked M=8192; 32 extra rows land in S padding):
  // S[c] = E[c-1] + E[c-2]@W^8 + E[c-3]@W^16, c = 1..255
  gemmA<<<dim3(SROWS / 128, H_DIM / 128), 256, 0, stream>>>(
      Eext + 2 * (size_t)BLK, 1024, Bstack + 7 * HH, H_DIM,
      Eext + 3 * (size_t)BLK, 1024, S + (size_t)BLK, 1024, nullptr);
  gemmA<<<dim3(SROWS / 128, H_DIM / 128), 256, 0, stream>>>(
      Eext + 1 * (size_t)BLK, 1024, P16T, H_DIM,
      S + (size_t)BLK, 1024, S + (size_t)BLK, 1024, nullptr);

  // Corrections + final assembly: out[c*8+jm] = UL[c][jm] + S[c] @ W^{jm+1}
  gemm256<<<dim3(SROWS / 256, ULW / 256), 512, 0, stream>>>(
      S, Bstack, UL, out, H_DIM, KC * BATCH);

  copy_hlast<<<dim3(BATCH), 256, 0, stream>>>(out);
}

// Round 12
// 802.984 us; speedup vs baseline: 1.7760x; 1.0103x over previous
//
#include <hip/hip_runtime.h>

typedef __attribute__((ext_vector_type(8))) short short8;
typedef __attribute__((ext_vector_type(4))) short short4v;
typedef __attribute__((ext_vector_type(4))) float f32x4;

#define DEV __device__ __forceinline__

constexpr int T_LEN  = 2048;
constexpr int BATCH  = 32;
constexpr int F_IN   = 64;
constexpr int H_DIM  = 1024;
constexpr int HQ     = 256;
constexpr int KC     = 8;                // timesteps per chunk
constexpr int NCHUNK = T_LEN / KC;       // 256
constexpr int SROWS  = NCHUNK * BATCH;   // 8192 state rows
constexpr int JT     = 8;                // correction taps (W^1..W^8)
constexpr int BLK    = BATCH * H_DIM;    // elems per chunk-block (32x1024)
constexpr int ULW    = JT * H_DIM;       // UL row width = 8192

DEV unsigned short f2bf(float f) {
  union { float f; unsigned u; } v; v.f = f;
  return (unsigned short)((v.u + 0x7fffu + ((v.u >> 16) & 1u)) >> 16);
}
DEV float bf2f(unsigned short s) {
  union { unsigned u; float f; } v; v.u = ((unsigned)s) << 16;
  return v.f;
}

DEV void gload16(const unsigned short* src, unsigned short* ldsDst) {
  __builtin_amdgcn_global_load_lds(
      (const __attribute__((address_space(1))) void*)src,
      (__attribute__((address_space(3))) void*)ldsDst, 16, 0, 0);
}

// Build W_uh as W^T (row-major [n][k] -> Bstack block 0) and W row-major.
__global__ void build_wuh(const float* __restrict__ cr, const float* __restrict__ ci,
                          const float* __restrict__ cj, const float* __restrict__ ck,
                          unsigned short* __restrict__ WT, unsigned short* __restrict__ Wrow) {
  int id = blockIdx.x * 256 + threadIdx.x;   // id = n*1024 + k
  int n = id >> 10, k = id & 1023;
  int q = n >> 8, b = n & 255, p = k >> 8, a = k & 255;
  const float* comps[4] = {cr, ci, cj, ck};
  const int   csel[16] = {0,1,2,3, 1,0,3,2, 2,3,0,1, 3,2,1,0};
  const float csgn[16] = {1.f,-1.f,-1.f,-1.f, 1.f,1.f,-1.f,1.f,
                          1.f,1.f,1.f,-1.f, 1.f,-1.f,1.f,1.f};
  float v = csgn[q*4+p] * comps[csel[q*4+p]][a*HQ + b];
  unsigned short bv = f2bf(v);
  WT[(size_t)n * 1024 + k] = bv;
  Wrow[(size_t)k * 1024 + n] = bv;
}

// Build W_wx^T (bf16, [n=1024][k=64]).
__global__ void build_wwx(const float* __restrict__ cr, const float* __restrict__ ci,
                          const float* __restrict__ cj, const float* __restrict__ ck,
                          unsigned short* __restrict__ WT) {
  int id = blockIdx.x * 256 + threadIdx.x;   // id = n*64 + k
  int n = id >> 6, k = id & 63;
  int q = n >> 8, b = n & 255, p = k >> 4, a = k & 15;
  const float* comps[4] = {cr, ci, cj, ck};
  const int   csel[16] = {0,1,2,3, 1,0,3,2, 2,3,0,1, 3,2,1,0};
  const float csgn[16] = {1.f,-1.f,-1.f,-1.f, 1.f,1.f,-1.f,1.f,
                          1.f,1.f,1.f,-1.f, 1.f,-1.f,1.f,1.f};
  float v = csgn[q*4+p] * comps[csel[q*4+p]][a*HQ + b];
  WT[(size_t)n * 64 + k] = f2bf(v);
}

__global__ void build_bias(const float* __restrict__ a, const float* __restrict__ b,
                           float* __restrict__ o) {
  int i = blockIdx.x * 256 + threadIdx.x;
  if (i < H_DIM) o[i] = a[i] + b[i];
}

// Gather fp32 rows -> contiguous bf16 rows (h0 staging).
__global__ void gather_bf16(unsigned short* __restrict__ dst, const float* __restrict__ src) {
  int r = blockIdx.x, tid = threadIdx.x;
  const float4* s = (const float4*)(src + (size_t)r * H_DIM);
  float4 v = s[tid];
  short4v o;
  o[0] = (short)f2bf(v.x); o[1] = (short)f2bf(v.y);
  o[2] = (short)f2bf(v.z); o[3] = (short)f2bf(v.w);
  *(short4v*)(dst + (size_t)r * H_DIM + tid * 4) = o;
}

__global__ void copy_hlast(float* __restrict__ out) {
  int b = blockIdx.x, tid = threadIdx.x;
  const float4* s = (const float4*)(out + ((size_t)(T_LEN - 1) * BATCH + b) * H_DIM);
  float4* d = (float4*)(out + (size_t)T_LEN * BATCH * H_DIM + (size_t)b * H_DIM);
  d[tid] = s[tid];
}

// ---------------- r4-proven GEMM engine (gemm_u + powers only) ----------------
template<bool AF32, int BM, int BN>
__launch_bounds__(256)
__global__ void gemm2(const void* __restrict__ Ap, int lda,
                      const unsigned short* __restrict__ Bt,
                      int M, int N, int K,
                      const float* __restrict__ bias,
                      const unsigned short* __restrict__ addBF, int strideBF,
                      unsigned short* __restrict__ stateOut, int strideS, int smode,
                      unsigned short* __restrict__ stateOutC,
                      unsigned short* __restrict__ stateOutT) {
  constexpr int TM = BM / 2, TN = BN / 2;    // 2x2 waves
  constexpr int FM = TM / 16, FN = TN / 16;
  __shared__ __align__(16) unsigned short Al[BM * 32];
  __shared__ __align__(16) unsigned short Bl[BN * 32];

  const int tid = threadIdx.x;
  const int lane = tid & 63, w = tid >> 6;
  const int bm0 = blockIdx.x * BM, bn0 = blockIdx.y * BN;
  const int wm = (w >> 1) * TM, wn = (w & 1) * TN;
  const int lr = lane & 15, lk = (lane >> 4) * 8;

  f32x4 acc[FM][FN];
#pragma unroll
  for (int i = 0; i < FM; ++i)
#pragma unroll
    for (int j = 0; j < FN; ++j)
#pragma unroll
      for (int q = 0; q < 4; ++q) acc[i][j][q] = 0.f;

  for (int kt = 0; kt < K; kt += 32) {
    if constexpr (AF32) {
#pragma unroll
      for (int ch = 0; ch < BM / 64; ++ch) {
        int c = ch * 256 + tid;
        int row = c >> 2, kp = (c & 3) * 8;
        int gr = bm0 + row;
        short8 v;
#pragma unroll
        for (int e = 0; e < 8; ++e) v[e] = 0;
        if (gr < M) {
          const float* a = (const float*)Ap + (size_t)gr * lda + kt + kp;
          float4 x0 = *(const float4*)a;
          float4 x1 = *(const float4*)(a + 4);
          v[0] = (short)f2bf(x0.x); v[1] = (short)f2bf(x0.y);
          v[2] = (short)f2bf(x0.z); v[3] = (short)f2bf(x0.w);
          v[4] = (short)f2bf(x1.x); v[5] = (short)f2bf(x1.y);
          v[6] = (short)f2bf(x1.z); v[7] = (short)f2bf(x1.w);
        }
        *(short8*)&Al[c * 8] = v;
      }
    } else {
#pragma unroll
      for (int ch = 0; ch < BM / 64; ++ch) {
        int c = ch * 256 + tid;
        int row = c >> 2, kp = (c & 3) * 8;
        int gr = bm0 + row;
        if (gr >= M) gr = M - 1;   // clamp: safe load, output masked later
        const unsigned short* src = (const unsigned short*)Ap + (size_t)gr * lda + kt + kp;
        gload16(src, &Al[c * 8]);
      }
    }
#pragma unroll
    for (int ch = 0; ch < BN / 64; ++ch) {
      int c = ch * 256 + tid;
      int row = c >> 2, kp = (c & 3) * 8;
      const unsigned short* src = Bt + (size_t)(bn0 + row) * K + kt + kp;
      gload16(src, &Bl[c * 8]);
    }
    __syncthreads();
    short8 af[FM], bfr[FN];
#pragma unroll
    for (int i = 0; i < FM; ++i) af[i] = *(const short8*)&Al[(wm + i * 16 + lr) * 32 + lk];
#pragma unroll
    for (int j = 0; j < FN; ++j) bfr[j] = *(const short8*)&Bl[(wn + j * 16 + lr) * 32 + lk];
#pragma unroll
    for (int i = 0; i < FM; ++i)
#pragma unroll
      for (int j = 0; j < FN; ++j)
        acc[i][j] = __builtin_amdgcn_mfma_f32_16x16x32_bf16(af[i], bfr[j], acc[i][j], 0, 0, 0);
    __syncthreads();
  }

#pragma unroll
  for (int i = 0; i < FM; ++i) {
    const int r0 = bm0 + wm + i * 16 + (lane >> 4) * 4;
#pragma unroll
    for (int j = 0; j < FN; ++j) {
      const int n = bn0 + wn + j * 16 + (lane & 15);
      short4v tv;
#pragma unroll
      for (int q = 0; q < 4; ++q) {
        int r = r0 + q;
        if (r >= M) continue;
        float v = acc[i][j][q];
        if (bias) v += bias[n];
        if (addBF) v += bf2f(addBF[(size_t)r * strideBF + n]);
        unsigned short bv = f2bf(v);
        if (stateOut) {
          if (smode == 0) {
            stateOut[(size_t)r * strideS + n] = bv;
          } else {
            int srow = (r >> 8) * 32 + (r & 31);
            int scol = ((r >> 5) & 7) * H_DIM + n;
            stateOut[(size_t)srow * strideS + scol] = bv;
          }
        }
        if (stateOutC) stateOutC[(size_t)r * N + n] = bv;
        tv[q] = (short)bv;
      }
      if (stateOutT && r0 < M)
        *(short4v*)(stateOutT + (size_t)n * M + r0) = tv;
    }
  }
}

// --------- 128x128 / BK=64 counted-vmcnt GEMM (pass A + S-fix) ---------
// Direct transplant of gemm256's verified schedule (0 bank conflicts, r9/r10)
// to 4 waves (2x2, 64x64/wave), LDS 64 KB -> 2 blocks/CU. Same T2 XOR-swizzle
// (linear gload dest + inverse-swizzled source + swizzled ds_read), same
// prologue {stage t0,t1; vmcnt(8)} and per-tile {phases; barrier; stage t+2;
// vmcnt(8); barrier} (8 gload16/tile/wave -> identical count arithmetic).
// C = A*Bt^T + addBF (bf16), written bf16 to stateOut (+optional stateOutC).
// M = gridDim.x*128 exactly (no masking).
__launch_bounds__(256)
__global__ void gemmA(const unsigned short* __restrict__ A, int lda,
                      const unsigned short* __restrict__ Bt, int K,
                      const unsigned short* __restrict__ addBF, int strideBF,
                      unsigned short* __restrict__ stateOut, int strideS,
                      unsigned short* __restrict__ stateOutC) {
  __shared__ __align__(16) unsigned short As[2][128][64];
  __shared__ __align__(16) unsigned short Bs[2][128][64];

  const int tid = threadIdx.x;
  const int lane = tid & 63, w = tid >> 6;
  const int wm = w >> 1, wn = w & 1;          // 2x2 wave grid
  const int lr = lane & 15, hi = lane >> 4;
  const int bm0 = blockIdx.x * 128, bn0 = blockIdx.y * 128;

  f32x4 acc[4][4];
#pragma unroll
  for (int i = 0; i < 4; ++i)
#pragma unroll
    for (int j = 0; j < 4; ++j)
#pragma unroll
      for (int q = 0; q < 4; ++q) acc[i][j][q] = 0.f;

  auto stageTile = [&](int b, int t) {
    const int kt = t * 64;
#pragma unroll
    for (int li = 0; li < 4; ++li) {
      int s = li * 256 + tid;                  // 0..1023 slots of 16B
      int row = s >> 3, c16 = s & 7;
      gload16(A + (size_t)(bm0 + row) * lda + kt + ((c16 ^ (row & 7)) << 3),
              &As[b][row][c16 * 8]);
    }
#pragma unroll
    for (int li = 0; li < 4; ++li) {
      int s = li * 256 + tid;
      int row = s >> 3, c16 = s & 7;
      gload16(Bt + (size_t)(bn0 + row) * K + kt + ((c16 ^ (row & 7)) << 3),
              &Bs[b][row][c16 * 8]);
    }
  };

  short8 af[4][2];
  auto phase = [&](int b, int nh, bool firstPhase) {
    if (firstPhase) {
#pragma unroll
      for (int mf = 0; mf < 4; ++mf)
#pragma unroll
        for (int kk = 0; kk < 2; ++kk) {
          int rl = wm * 64 + mf * 16 + lr;
          int c16 = ((kk << 2) + hi) ^ (lr & 7);
          af[mf][kk] = *(const short8*)&As[b][rl][c16 * 8];
        }
    }
    short8 bw[2][2];
#pragma unroll
    for (int nf = 0; nf < 2; ++nf)
#pragma unroll
      for (int kk = 0; kk < 2; ++kk) {
        int rn = wn * 64 + (nh * 2 + nf) * 16 + lr;
        int c16 = ((kk << 2) + hi) ^ (lr & 7);
        bw[nf][kk] = *(const short8*)&Bs[b][rn][c16 * 8];
      }
    asm volatile("s_waitcnt lgkmcnt(0)" ::: "memory");
    __builtin_amdgcn_sched_barrier(0);
    __builtin_amdgcn_s_setprio(1);
#pragma unroll
    for (int mf = 0; mf < 4; ++mf)
#pragma unroll
      for (int nf = 0; nf < 2; ++nf)
#pragma unroll
        for (int kk = 0; kk < 2; ++kk)
          acc[mf][nh * 2 + nf] = __builtin_amdgcn_mfma_f32_16x16x32_bf16(
              af[mf][kk], bw[nf][kk], acc[mf][nh * 2 + nf], 0, 0, 0);
    __builtin_amdgcn_s_setprio(0);
    __builtin_amdgcn_sched_barrier(0);
  };

  const int NT = K / 64;                       // 16
  stageTile(0, 0);
  stageTile(1, 1);
  asm volatile("s_waitcnt vmcnt(8)" ::: "memory");   // tile 0 landed; tile 1 in flight
  __builtin_amdgcn_s_barrier();
  asm volatile("" ::: "memory");
  __builtin_amdgcn_sched_barrier(0);

  for (int t = 0; t < NT; ++t) {
    const int b = t & 1;
    phase(b, 0, true); phase(b, 1, false);
    asm volatile("" ::: "memory");
    __builtin_amdgcn_s_barrier();              // all waves done reading buf b
    asm volatile("" ::: "memory");
    if (t + 2 < NT) {
      stageTile(b, t + 2);
      asm volatile("s_waitcnt vmcnt(8)" ::: "memory"); // t+1 landed; t+2 in flight
    } else {
      asm volatile("s_waitcnt vmcnt(0)" ::: "memory"); // tail drain
    }
    __builtin_amdgcn_s_barrier();
    asm volatile("" ::: "memory");
    __builtin_amdgcn_sched_barrier(0);
  }

  // epilogue: bf16 out = acc + addBF
#pragma unroll
  for (int mf = 0; mf < 4; ++mf) {
    const int r0 = bm0 + wm * 64 + mf * 16 + hi * 4;
#pragma unroll
    for (int nf = 0; nf < 4; ++nf) {
      const int n = bn0 + wn * 64 + nf * 16 + lr;
#pragma unroll
      for (int q = 0; q < 4; ++q) {
        int r = r0 + q;
        float v = acc[mf][nf][q];
        if (addBF) v += bf2f(addBF[(size_t)r * strideBF + n]);
        unsigned short bv = f2bf(v);
        stateOut[(size_t)r * strideS + n] = bv;
        if (stateOutC) stateOutC[(size_t)r * H_DIM + n] = bv;
      }
    }
  }
}

// ------------- 256x256 / BK=64 phase-structured GEMM (corr only) -------------
__launch_bounds__(512)
__global__ void gemm256(const unsigned short* __restrict__ A,
                        const unsigned short* __restrict__ Bt,
                        const unsigned short* __restrict__ addBF,
                        float* __restrict__ outF,
                        int K, int mapStride) {
  __shared__ __align__(16) unsigned short As[2][2][128][64];
  __shared__ __align__(16) unsigned short Bs[2][2][128][64];

  const int tid = threadIdx.x;
  const int lane = tid & 63, w = tid >> 6;
  const int wm = w >> 2, wn = w & 3;          // 2x4 wave grid
  const int lr = lane & 15, hi = lane >> 4;
  const int bm0 = blockIdx.x * 256, bn0 = blockIdx.y * 256;

  f32x4 acc[8][4];
#pragma unroll
  for (int i = 0; i < 8; ++i)
#pragma unroll
    for (int j = 0; j < 4; ++j)
#pragma unroll
      for (int q = 0; q < 4; ++q) acc[i][j][q] = 0.f;

  auto stageTile = [&](int b, int t) {
    const int kt = t * 64;
#pragma unroll
    for (int h = 0; h < 2; ++h)
#pragma unroll
      for (int li = 0; li < 2; ++li) {
        int s = li * 512 + tid;              // 0..1023 slots of 16B
        int row = s >> 3, c16 = s & 7;
        gload16(A + (size_t)(bm0 + h * 128 + row) * K + kt + ((c16 ^ (row & 7)) << 3),
                &As[b][h][row][c16 * 8]);
      }
#pragma unroll
    for (int h = 0; h < 2; ++h)
#pragma unroll
      for (int li = 0; li < 2; ++li) {
        int s = li * 512 + tid;
        int row = s >> 3, c16 = s & 7;
        gload16(Bt + (size_t)(bn0 + h * 128 + row) * K + kt + ((c16 ^ (row & 7)) << 3),
                &Bs[b][h][row][c16 * 8]);
      }
  };

  auto phase = [&](int b, int mh, int nh) {
    short8 af[4][2], bw[2][2];
#pragma unroll
    for (int mf = 0; mf < 4; ++mf)
#pragma unroll
      for (int kk = 0; kk < 2; ++kk) {
        int rl = mh * 64 + mf * 16 + lr;
        int c16 = ((kk << 2) + hi) ^ (lr & 7);
        af[mf][kk] = *(const short8*)&As[b][wm][rl][c16 * 8];
      }
#pragma unroll
    for (int nf = 0; nf < 2; ++nf)
#pragma unroll
      for (int kk = 0; kk < 2; ++kk) {
        int rn = (wn & 1) * 64 + (nh * 2 + nf) * 16 + lr;
        int c16 = ((kk << 2) + hi) ^ (lr & 7);
        bw[nf][kk] = *(const short8*)&Bs[b][wn >> 1][rn][c16 * 8];
      }
    asm volatile("s_waitcnt lgkmcnt(0)" ::: "memory");
    __builtin_amdgcn_sched_barrier(0);
    __builtin_amdgcn_s_setprio(1);
#pragma unroll
    for (int mf = 0; mf < 4; ++mf)
#pragma unroll
      for (int nf = 0; nf < 2; ++nf)
#pragma unroll
        for (int kk = 0; kk < 2; ++kk)
          acc[mh * 4 + mf][nh * 2 + nf] = __builtin_amdgcn_mfma_f32_16x16x32_bf16(
              af[mf][kk], bw[nf][kk], acc[mh * 4 + mf][nh * 2 + nf], 0, 0, 0);
    __builtin_amdgcn_s_setprio(0);
    __builtin_amdgcn_sched_barrier(0);
  };

  const int NT = K / 64;                       // 16
  stageTile(0, 0);
  stageTile(1, 1);
  asm volatile("s_waitcnt vmcnt(8)" ::: "memory");   // tile 0 landed; tile 1 in flight
  __builtin_amdgcn_s_barrier();
  asm volatile("" ::: "memory");
  __builtin_amdgcn_sched_barrier(0);

  for (int t = 0; t < NT; ++t) {
    const int b = t & 1;
    phase(b, 0, 0); phase(b, 0, 1); phase(b, 1, 0); phase(b, 1, 1);
    asm volatile("" ::: "memory");
    __builtin_amdgcn_s_barrier();
    asm volatile("" ::: "memory");
    if (t + 2 < NT) {
      stageTile(b, t + 2);
      asm volatile("s_waitcnt vmcnt(8)" ::: "memory"); // t+1 landed; t+2 stays in flight
    } else {
      asm volatile("s_waitcnt vmcnt(0)" ::: "memory"); // tail drain
    }
    __builtin_amdgcn_s_barrier();
    asm volatile("" ::: "memory");
    __builtin_amdgcn_sched_barrier(0);
  }

  // epilogue: out = acc + UL (bf16), single fp32 write through chunk mapping
#pragma unroll
  for (int i = 0; i < 8; ++i) {
    const int r0 = bm0 + wm * 128 + i * 16 + hi * 4;
#pragma unroll
    for (int j = 0; j < 4; ++j) {
      const int n = bn0 + wn * 64 + j * 16 + lr;
      const int col = n & 1023, jm = n >> 10;
#pragma unroll
      for (int q = 0; q < 4; ++q) {
        int r = r0 + q;
        float v = acc[i][j][q] + bf2f(addBF[(size_t)r * ULW + n]);
        int g = (r >> 5) * mapStride + jm * BATCH + (r & 31);
        outF[(size_t)g * H_DIM + col] = v;
      }
    }
  }
}

extern "C" void kernel_launch(void* const* d_in, const int* in_sizes, int n_in,
                              void* d_out, int out_size, void* d_ws, size_t ws_size,
                              hipStream_t stream) {
  const float* x   = (const float*)d_in[0];
  const float* h0  = (const float*)d_in[1];
  const float* wxr = (const float*)d_in[2];
  const float* wxi = (const float*)d_in[3];
  const float* wxj = (const float*)d_in[4];
  const float* wxk = (const float*)d_in[5];
  const float* wxb = (const float*)d_in[6];
  const float* uhr = (const float*)d_in[7];
  const float* uhi = (const float*)d_in[8];
  const float* uhj = (const float*)d_in[9];
  const float* uhk = (const float*)d_in[10];
  const float* uhb = (const float*)d_in[11];
  float* out = (float*)d_out;

  constexpr size_t HH = (size_t)H_DIM * H_DIM;   // 1M elems
  char* ws = (char*)d_ws;
  size_t off = 0;
  auto take = [&](size_t bytes) { void* p = ws + off; off += (bytes + 255) & ~(size_t)255; return p; };
  unsigned short* Bstack = (unsigned short*)take(JT * HH * 2);       // (W^1..W^8)^T, 16 MB
  unsigned short* Wrow   = (unsigned short*)take(HH * 2);
  unsigned short* WwxT   = (unsigned short*)take((size_t)H_DIM * F_IN * 2);
  float*          bias   = (float*)take(H_DIM * 4);
  unsigned short* P2row  = (unsigned short*)take(HH * 2);
  unsigned short* P34row = (unsigned short*)take(2 * HH * 2);        // [1024][2048]
  unsigned short* P58row = (unsigned short*)take(4 * HH * 2);        // [1024][4096]
  unsigned short* P16T   = (unsigned short*)take(HH * 2);
  // Eext: 259 chunk-blocks. Eext[i] = E[i-3]; E[m]=Lend_m (m>=0), E[-1]=h0, E[<-1]=0.
  unsigned short* Eext   = (unsigned short*)take((size_t)(NCHUNK + 3) * BLK * 2);
  // S padded +BATCH rows: unmasked M=8192 S-fix writes spill into padding.
  unsigned short* S      = (unsigned short*)take((size_t)(SROWS + BATCH) * H_DIM * 2);
  // UL: bf16 [c*32+b][j*1024+col]; U written by gemm_u, overwritten by L in pass A.
  unsigned short* UL     = (unsigned short*)take((size_t)SROWS * ULW * 2);  // 128 MB
  if (off > ws_size) return;  // workspace too small; fail visibly

  build_wuh<<<dim3(HH / 256), 256, 0, stream>>>(uhr, uhi, uhj, uhk, Bstack, Wrow);
  build_wwx<<<dim3((H_DIM * F_IN) / 256), 256, 0, stream>>>(wxr, wxi, wxj, wxk, WwxT);
  build_bias<<<dim3(4), 256, 0, stream>>>(wxb, uhb, bias);

  // U = x @ W_wx + (wx_b + uh_b) -> UL bf16, qsplit layout
  gemm2<true, 128, 128><<<dim3(T_LEN * BATCH / 128, H_DIM / 128), 256, 0, stream>>>(
      x, F_IN, WwxT, T_LEN * BATCH, H_DIM, F_IN,
      bias, nullptr, 0, UL, ULW, 1, nullptr, nullptr);

  // Matrix powers (log-doubling); Bstack block m-1 = (W^m)^T.
  gemm2<false, 64, 128><<<dim3(16, 8), 256, 0, stream>>>(        // P2 = W@W
      Wrow, 1024, Bstack, 1024, 1024, 1024,
      nullptr, nullptr, 0, P2row, 1024, 0, nullptr, Bstack + 1 * HH);
  gemm2<false, 64, 128><<<dim3(16, 16), 256, 0, stream>>>(       // [P3,P4] = P2@[P1,P2]
      P2row, 1024, Bstack, 1024, 2048, 1024,
      nullptr, nullptr, 0, P34row, 2048, 0, nullptr, Bstack + 2 * HH);
  gemm2<false, 64, 128><<<dim3(16, 32), 256, 0, stream>>>(       // [P5..P8] = P4@[P1..P4]
      P34row + 1024, 2048, Bstack, 1024, 4096, 1024,
      nullptr, nullptr, 0, P58row, 4096, 0, nullptr, Bstack + 4 * HH);
  gemm2<false, 64, 128><<<dim3(16, 8), 256, 0, stream>>>(        // P16 = P8@P8
      P58row + 3 * 1024, 4096, Bstack + 7 * HH, 1024, 1024, 1024,
      nullptr, nullptr, 0, nullptr, 0, 0, nullptr, P16T);

  // Guard blocks + s_0
  hipMemsetAsync(Eext, 0, 2 * (size_t)BLK * 2, stream);             // E[-3], E[-2] = 0
  gather_bf16<<<dim3(BATCH), 256, 0, stream>>>(Eext + 2 * (size_t)BLK, h0); // E[-1]=h0
  gather_bf16<<<dim3(BATCH), 256, 0, stream>>>(S, h0);              // s_0 = h0

  // Pass A: L_j = L_{j-1}@W + U_j, all in UL col-blocks (bf16 only, gemmA).
  for (int j = 1; j < KC; ++j) {
    unsigned short* soC = (j == KC - 1) ? (Eext + 3 * (size_t)BLK) : nullptr; // Lend->Eext
    gemmA<<<dim3(SROWS / 128, H_DIM / 128), 256, 0, stream>>>(
        UL + (size_t)(j - 1) * H_DIM, ULW, Bstack, H_DIM,
        UL + (size_t)j * H_DIM, ULW,
        UL + (size_t)j * H_DIM, ULW, soC);
  }

  // S-fix (3-tap, unmasked M=8192; 32 extra rows land in S padding):
  // S[c] = E[c-1] + E[c-2]@W^8 + E[c-3]@W^16, c = 1..255
  gemmA<<<dim3(SROWS / 128, H_DIM / 128), 256, 0, stream>>>(
      Eext + 2 * (size_t)BLK, 1024, Bstack + 7 * HH, H_DIM,
      Eext + 3 * (size_t)BLK, 1024, S + (size_t)BLK, 1024, nullptr);
  gemmA<<<dim3(SROWS / 128, H_DIM / 128), 256, 0, stream>>>(
      Eext + 1 * (size_t)BLK, 1024, P16T, H_DIM,
      S + (size_t)BLK, 1024, S + (size_t)BLK, 1024, nullptr);

  // Corrections + final assembly: out[c*8+jm] = UL[c][jm] + S[c] @ W^{jm+1}
  gemm256<<<dim3(SROWS / 256, ULW / 256), 512, 0, stream>>>(
      S, Bstack, UL, out, H_DIM, KC * BATCH);

  copy_hlast<<<dim3(BATCH), 256, 0, stream>>>(out);
}

// Round 13
// 793.209 us; speedup vs baseline: 1.7979x; 1.0123x over previous
//
#include <hip/hip_runtime.h>

typedef __attribute__((ext_vector_type(8))) short short8;
typedef __attribute__((ext_vector_type(4))) short short4v;
typedef __attribute__((ext_vector_type(4))) float f32x4;

#define DEV __device__ __forceinline__

constexpr int T_LEN  = 2048;
constexpr int BATCH  = 32;
constexpr int F_IN   = 64;
constexpr int H_DIM  = 1024;
constexpr int HQ     = 256;
constexpr int KC     = 8;                // timesteps per chunk
constexpr int NCHUNK = T_LEN / KC;       // 256
constexpr int SROWS  = NCHUNK * BATCH;   // 8192 state rows
constexpr int JT     = 8;                // correction taps (W^1..W^8)
constexpr int BLK    = BATCH * H_DIM;    // elems per chunk-block (32x1024)
constexpr int ULW    = JT * H_DIM;       // UL row width = 8192

DEV unsigned short f2bf(float f) {
  union { float f; unsigned u; } v; v.f = f;
  return (unsigned short)((v.u + 0x7fffu + ((v.u >> 16) & 1u)) >> 16);
}
DEV float bf2f(unsigned short s) {
  union { unsigned u; float f; } v; v.u = ((unsigned)s) << 16;
  return v.f;
}

DEV void gload16(const unsigned short* src, unsigned short* ldsDst) {
  __builtin_amdgcn_global_load_lds(
      (const __attribute__((address_space(1))) void*)src,
      (__attribute__((address_space(3))) void*)ldsDst, 16, 0, 0);
}

// Build W_uh as W^T (row-major [n][k] -> Bstack block 0) and W row-major.
__global__ void build_wuh(const float* __restrict__ cr, const float* __restrict__ ci,
                          const float* __restrict__ cj, const float* __restrict__ ck,
                          unsigned short* __restrict__ WT, unsigned short* __restrict__ Wrow) {
  int id = blockIdx.x * 256 + threadIdx.x;   // id = n*1024 + k
  int n = id >> 10, k = id & 1023;
  int q = n >> 8, b = n & 255, p = k >> 8, a = k & 255;
  const float* comps[4] = {cr, ci, cj, ck};
  const int   csel[16] = {0,1,2,3, 1,0,3,2, 2,3,0,1, 3,2,1,0};
  const float csgn[16] = {1.f,-1.f,-1.f,-1.f, 1.f,1.f,-1.f,1.f,
                          1.f,1.f,1.f,-1.f, 1.f,-1.f,1.f,1.f};
  float v = csgn[q*4+p] * comps[csel[q*4+p]][a*HQ + b];
  unsigned short bv = f2bf(v);
  WT[(size_t)n * 1024 + k] = bv;
  Wrow[(size_t)k * 1024 + n] = bv;
}

// Build W_wx^T (bf16, [n=1024][k=64]).
__global__ void build_wwx(const float* __restrict__ cr, const float* __restrict__ ci,
                          const float* __restrict__ cj, const float* __restrict__ ck,
                          unsigned short* __restrict__ WT) {
  int id = blockIdx.x * 256 + threadIdx.x;   // id = n*64 + k
  int n = id >> 6, k = id & 63;
  int q = n >> 8, b = n & 255, p = k >> 4, a = k & 15;
  const float* comps[4] = {cr, ci, cj, ck};
  const int   csel[16] = {0,1,2,3, 1,0,3,2, 2,3,0,1, 3,2,1,0};
  const float csgn[16] = {1.f,-1.f,-1.f,-1.f, 1.f,1.f,-1.f,1.f,
                          1.f,1.f,1.f,-1.f, 1.f,-1.f,1.f,1.f};
  float v = csgn[q*4+p] * comps[csel[q*4+p]][a*HQ + b];
  WT[(size_t)n * 64 + k] = f2bf(v);
}

__global__ void build_bias(const float* __restrict__ a, const float* __restrict__ b,
                           float* __restrict__ o) {
  int i = blockIdx.x * 256 + threadIdx.x;
  if (i < H_DIM) o[i] = a[i] + b[i];
}

// Gather fp32 rows -> contiguous bf16 rows (h0 staging).
__global__ void gather_bf16(unsigned short* __restrict__ dst, const float* __restrict__ src) {
  int r = blockIdx.x, tid = threadIdx.x;
  const float4* s = (const float4*)(src + (size_t)r * H_DIM);
  float4 v = s[tid];
  short4v o;
  o[0] = (short)f2bf(v.x); o[1] = (short)f2bf(v.y);
  o[2] = (short)f2bf(v.z); o[3] = (short)f2bf(v.w);
  *(short4v*)(dst + (size_t)r * H_DIM + tid * 4) = o;
}

__global__ void copy_hlast(float* __restrict__ out) {
  int b = blockIdx.x, tid = threadIdx.x;
  const float4* s = (const float4*)(out + ((size_t)(T_LEN - 1) * BATCH + b) * H_DIM);
  float4* d = (float4*)(out + (size_t)T_LEN * BATCH * H_DIM + (size_t)b * H_DIM);
  d[tid] = s[tid];
}

// ---------------- r4-proven GEMM engine (gemm_u + powers only) ----------------
template<bool AF32, int BM, int BN>
__launch_bounds__(256)
__global__ void gemm2(const void* __restrict__ Ap, int lda,
                      const unsigned short* __restrict__ Bt,
                      int M, int N, int K,
                      const float* __restrict__ bias,
                      const unsigned short* __restrict__ addBF, int strideBF,
                      unsigned short* __restrict__ stateOut, int strideS, int smode,
                      unsigned short* __restrict__ stateOutC,
                      unsigned short* __restrict__ stateOutT) {
  constexpr int TM = BM / 2, TN = BN / 2;    // 2x2 waves
  constexpr int FM = TM / 16, FN = TN / 16;
  __shared__ __align__(16) unsigned short Al[BM * 32];
  __shared__ __align__(16) unsigned short Bl[BN * 32];

  const int tid = threadIdx.x;
  const int lane = tid & 63, w = tid >> 6;
  const int bm0 = blockIdx.x * BM, bn0 = blockIdx.y * BN;
  const int wm = (w >> 1) * TM, wn = (w & 1) * TN;
  const int lr = lane & 15, lk = (lane >> 4) * 8;

  f32x4 acc[FM][FN];
#pragma unroll
  for (int i = 0; i < FM; ++i)
#pragma unroll
    for (int j = 0; j < FN; ++j)
#pragma unroll
      for (int q = 0; q < 4; ++q) acc[i][j][q] = 0.f;

  for (int kt = 0; kt < K; kt += 32) {
    if constexpr (AF32) {
#pragma unroll
      for (int ch = 0; ch < BM / 64; ++ch) {
        int c = ch * 256 + tid;
        int row = c >> 2, kp = (c & 3) * 8;
        int gr = bm0 + row;
        short8 v;
#pragma unroll
        for (int e = 0; e < 8; ++e) v[e] = 0;
        if (gr < M) {
          const float* a = (const float*)Ap + (size_t)gr * lda + kt + kp;
          float4 x0 = *(const float4*)a;
          float4 x1 = *(const float4*)(a + 4);
          v[0] = (short)f2bf(x0.x); v[1] = (short)f2bf(x0.y);
          v[2] = (short)f2bf(x0.z); v[3] = (short)f2bf(x0.w);
          v[4] = (short)f2bf(x1.x); v[5] = (short)f2bf(x1.y);
          v[6] = (short)f2bf(x1.z); v[7] = (short)f2bf(x1.w);
        }
        *(short8*)&Al[c * 8] = v;
      }
    } else {
#pragma unroll
      for (int ch = 0; ch < BM / 64; ++ch) {
        int c = ch * 256 + tid;
        int row = c >> 2, kp = (c & 3) * 8;
        int gr = bm0 + row;
        if (gr >= M) gr = M - 1;   // clamp: safe load, output masked later
        const unsigned short* src = (const unsigned short*)Ap + (size_t)gr * lda + kt + kp;
        gload16(src, &Al[c * 8]);
      }
    }
#pragma unroll
    for (int ch = 0; ch < BN / 64; ++ch) {
      int c = ch * 256 + tid;
      int row = c >> 2, kp = (c & 3) * 8;
      const unsigned short* src = Bt + (size_t)(bn0 + row) * K + kt + kp;
      gload16(src, &Bl[c * 8]);
    }
    __syncthreads();
    short8 af[FM], bfr[FN];
#pragma unroll
    for (int i = 0; i < FM; ++i) af[i] = *(const short8*)&Al[(wm + i * 16 + lr) * 32 + lk];
#pragma unroll
    for (int j = 0; j < FN; ++j) bfr[j] = *(const short8*)&Bl[(wn + j * 16 + lr) * 32 + lk];
#pragma unroll
    for (int i = 0; i < FM; ++i)
#pragma unroll
      for (int j = 0; j < FN; ++j)
        acc[i][j] = __builtin_amdgcn_mfma_f32_16x16x32_bf16(af[i], bfr[j], acc[i][j], 0, 0, 0);
    __syncthreads();
  }

#pragma unroll
  for (int i = 0; i < FM; ++i) {
    const int r0 = bm0 + wm + i * 16 + (lane >> 4) * 4;
#pragma unroll
    for (int j = 0; j < FN; ++j) {
      const int n = bn0 + wn + j * 16 + (lane & 15);
      short4v tv;
#pragma unroll
      for (int q = 0; q < 4; ++q) {
        int r = r0 + q;
        if (r >= M) continue;
        float v = acc[i][j][q];
        if (bias) v += bias[n];
        if (addBF) v += bf2f(addBF[(size_t)r * strideBF + n]);
        unsigned short bv = f2bf(v);
        if (stateOut) {
          if (smode == 0) {
            stateOut[(size_t)r * strideS + n] = bv;
          } else {
            int srow = (r >> 8) * 32 + (r & 31);
            int scol = ((r >> 5) & 7) * H_DIM + n;
            stateOut[(size_t)srow * strideS + scol] = bv;
          }
        }
        if (stateOutC) stateOutC[(size_t)r * N + n] = bv;
        tv[q] = (short)bv;
      }
      if (stateOutT && r0 < M)
        *(short4v*)(stateOutT + (size_t)n * M + r0) = tv;
    }
  }
}

// --------- 128x128 / BK=64 counted-vmcnt GEMM (pass A + S-fix) ---------
// r11-proven barrier/vmcnt skeleton (0 bank conflicts). r13 change: all 16
// fragment ds_reads issued per K-tile with NO manual lgkm/sched fences inside
// the compute section — compiler emits counted lgkmcnt and interleaves loads
// with the 32-MFMA cluster. MFMA kk-innermost order preserved (bit-identical).
__launch_bounds__(256)
__global__ void gemmA(const unsigned short* __restrict__ A, int lda,
                      const unsigned short* __restrict__ Bt, int K,
                      const unsigned short* __restrict__ addBF, int strideBF,
                      unsigned short* __restrict__ stateOut, int strideS,
                      unsigned short* __restrict__ stateOutC) {
  __shared__ __align__(16) unsigned short As[2][128][64];
  __shared__ __align__(16) unsigned short Bs[2][128][64];

  const int tid = threadIdx.x;
  const int lane = tid & 63, w = tid >> 6;
  const int wm = w >> 1, wn = w & 1;          // 2x2 wave grid
  const int lr = lane & 15, hi = lane >> 4;
  const int bm0 = blockIdx.x * 128, bn0 = blockIdx.y * 128;

  f32x4 acc[4][4];
#pragma unroll
  for (int i = 0; i < 4; ++i)
#pragma unroll
    for (int j = 0; j < 4; ++j)
#pragma unroll
      for (int q = 0; q < 4; ++q) acc[i][j][q] = 0.f;

  auto stageTile = [&](int b, int t) {
    const int kt = t * 64;
#pragma unroll
    for (int li = 0; li < 4; ++li) {
      int s = li * 256 + tid;                  // 0..1023 slots of 16B
      int row = s >> 3, c16 = s & 7;
      gload16(A + (size_t)(bm0 + row) * lda + kt + ((c16 ^ (row & 7)) << 3),
              &As[b][row][c16 * 8]);
    }
#pragma unroll
    for (int li = 0; li < 4; ++li) {
      int s = li * 256 + tid;
      int row = s >> 3, c16 = s & 7;
      gload16(Bt + (size_t)(bn0 + row) * K + kt + ((c16 ^ (row & 7)) << 3),
              &Bs[b][row][c16 * 8]);
    }
  };

  const int NT = K / 64;
  stageTile(0, 0);
  stageTile(1, 1);
  asm volatile("s_waitcnt vmcnt(8)" ::: "memory");   // tile 0 landed; tile 1 in flight
  __builtin_amdgcn_s_barrier();
  asm volatile("" ::: "memory");
  __builtin_amdgcn_sched_barrier(0);

  for (int t = 0; t < NT; ++t) {
    const int b = t & 1;
    short8 af[2][4], bw[2][4];
#pragma unroll
    for (int kk = 0; kk < 2; ++kk) {
      const int c16k = (kk << 2) + hi;
#pragma unroll
      for (int mf = 0; mf < 4; ++mf) {
        int rl = wm * 64 + mf * 16 + lr;
        af[kk][mf] = *(const short8*)&As[b][rl][(c16k ^ (lr & 7)) * 8];
      }
#pragma unroll
      for (int nf = 0; nf < 4; ++nf) {
        int rn = wn * 64 + nf * 16 + lr;
        bw[kk][nf] = *(const short8*)&Bs[b][rn][(c16k ^ (lr & 7)) * 8];
      }
    }
    __builtin_amdgcn_s_setprio(1);
#pragma unroll
    for (int mf = 0; mf < 4; ++mf)
#pragma unroll
      for (int nf = 0; nf < 4; ++nf)
#pragma unroll
        for (int kk = 0; kk < 2; ++kk)
          acc[mf][nf] = __builtin_amdgcn_mfma_f32_16x16x32_bf16(
              af[kk][mf], bw[kk][nf], acc[mf][nf], 0, 0, 0);
    __builtin_amdgcn_s_setprio(0);
    asm volatile("" ::: "memory");
    __builtin_amdgcn_s_barrier();              // all waves done reading buf b
    asm volatile("" ::: "memory");
    if (t + 2 < NT) {
      stageTile(b, t + 2);
      asm volatile("s_waitcnt vmcnt(8)" ::: "memory"); // t+1 landed; t+2 in flight
    } else {
      asm volatile("s_waitcnt vmcnt(0)" ::: "memory"); // tail drain
    }
    __builtin_amdgcn_s_barrier();
    asm volatile("" ::: "memory");
    __builtin_amdgcn_sched_barrier(0);
  }

  // epilogue: bf16 out = acc + addBF
#pragma unroll
  for (int mf = 0; mf < 4; ++mf) {
    const int r0 = bm0 + wm * 64 + mf * 16 + hi * 4;
#pragma unroll
    for (int nf = 0; nf < 4; ++nf) {
      const int n = bn0 + wn * 64 + nf * 16 + lr;
#pragma unroll
      for (int q = 0; q < 4; ++q) {
        int r = r0 + q;
        float v = acc[mf][nf][q];
        if (addBF) v += bf2f(addBF[(size_t)r * strideBF + n]);
        unsigned short bv = f2bf(v);
        stateOut[(size_t)r * strideS + n] = bv;
        if (stateOutC) stateOutC[(size_t)r * H_DIM + n] = bv;
      }
    }
  }
}

// ------------- 256x256 / BK=64 phase-structured GEMM (corr only) -------------
// r9-proven skeleton; r13: fragment dedupe (48 -> 24 ds_reads per K-tile per
// wave: A frags loaded once, B frags once) + no manual fences in compute
// section (compiler-scheduled counted lgkmcnt). MFMA kk-innermost preserved.
__launch_bounds__(512)
__global__ void gemm256(const unsigned short* __restrict__ A,
                        const unsigned short* __restrict__ Bt,
                        const unsigned short* __restrict__ addBF,
                        float* __restrict__ outF,
                        int K, int mapStride) {
  __shared__ __align__(16) unsigned short As[2][2][128][64];
  __shared__ __align__(16) unsigned short Bs[2][2][128][64];

  const int tid = threadIdx.x;
  const int lane = tid & 63, w = tid >> 6;
  const int wm = w >> 2, wn = w & 3;          // 2x4 wave grid
  const int lr = lane & 15, hi = lane >> 4;
  const int bm0 = blockIdx.x * 256, bn0 = blockIdx.y * 256;

  f32x4 acc[8][4];
#pragma unroll
  for (int i = 0; i < 8; ++i)
#pragma unroll
    for (int j = 0; j < 4; ++j)
#pragma unroll
      for (int q = 0; q < 4; ++q) acc[i][j][q] = 0.f;

  auto stageTile = [&](int b, int t) {
    const int kt = t * 64;
#pragma unroll
    for (int h = 0; h < 2; ++h)
#pragma unroll
      for (int li = 0; li < 2; ++li) {
        int s = li * 512 + tid;              // 0..1023 slots of 16B
        int row = s >> 3, c16 = s & 7;
        gload16(A + (size_t)(bm0 + h * 128 + row) * K + kt + ((c16 ^ (row & 7)) << 3),
                &As[b][h][row][c16 * 8]);
      }
#pragma unroll
    for (int h = 0; h < 2; ++h)
#pragma unroll
      for (int li = 0; li < 2; ++li) {
        int s = li * 512 + tid;
        int row = s >> 3, c16 = s & 7;
        gload16(Bt + (size_t)(bn0 + h * 128 + row) * K + kt + ((c16 ^ (row & 7)) << 3),
                &Bs[b][h][row][c16 * 8]);
      }
  };

  const int NT = K / 64;                       // 16
  stageTile(0, 0);
  stageTile(1, 1);
  asm volatile("s_waitcnt vmcnt(8)" ::: "memory");   // tile 0 landed; tile 1 in flight
  __builtin_amdgcn_s_barrier();
  asm volatile("" ::: "memory");
  __builtin_amdgcn_sched_barrier(0);

  for (int t = 0; t < NT; ++t) {
    const int b = t & 1;
    // per-kk: 12 frag reads then 32 MFMA; no fences -> compiler interleaves
#pragma unroll
    for (int kk = 0; kk < 2; ++kk) {
      const int c16k = (kk << 2) + hi;
      short8 af[8], bw[4];
#pragma unroll
      for (int m = 0; m < 8; ++m)
        af[m] = *(const short8*)&As[b][wm][m * 16 + lr][((c16k ^ (lr & 7))) * 8];
#pragma unroll
      for (int n2 = 0; n2 < 4; ++n2)
        bw[n2] = *(const short8*)&Bs[b][wn >> 1][(wn & 1) * 64 + n2 * 16 + lr]
                                   [((c16k ^ (lr & 7))) * 8];
      __builtin_amdgcn_s_setprio(1);
#pragma unroll
      for (int m = 0; m < 8; ++m)
#pragma unroll
        for (int n2 = 0; n2 < 4; ++n2)
          acc[m][n2] = __builtin_amdgcn_mfma_f32_16x16x32_bf16(
              af[m], bw[n2], acc[m][n2], 0, 0, 0);
      __builtin_amdgcn_s_setprio(0);
    }
    asm volatile("" ::: "memory");
    __builtin_amdgcn_s_barrier();
    asm volatile("" ::: "memory");
    if (t + 2 < NT) {
      stageTile(b, t + 2);
      asm volatile("s_waitcnt vmcnt(8)" ::: "memory"); // t+1 landed; t+2 stays in flight
    } else {
      asm volatile("s_waitcnt vmcnt(0)" ::: "memory"); // tail drain
    }
    __builtin_amdgcn_s_barrier();
    asm volatile("" ::: "memory");
    __builtin_amdgcn_sched_barrier(0);
  }

  // epilogue: out = acc + UL (bf16), single fp32 write through chunk mapping
#pragma unroll
  for (int i = 0; i < 8; ++i) {
    const int r0 = bm0 + wm * 128 + i * 16 + hi * 4;
#pragma unroll
    for (int j = 0; j < 4; ++j) {
      const int n = bn0 + wn * 64 + j * 16 + lr;
      const int col = n & 1023, jm = n >> 10;
#pragma unroll
      for (int q = 0; q < 4; ++q) {
        int r = r0 + q;
        float v = acc[i][j][q] + bf2f(addBF[(size_t)r * ULW + n]);
        int g = (r >> 5) * mapStride + jm * BATCH + (r & 31);
        outF[(size_t)g * H_DIM + col] = v;
      }
    }
  }
}

extern "C" void kernel_launch(void* const* d_in, const int* in_sizes, int n_in,
                              void* d_out, int out_size, void* d_ws, size_t ws_size,
                              hipStream_t stream) {
  const float* x   = (const float*)d_in[0];
  const float* h0  = (const float*)d_in[1];
  const float* wxr = (const float*)d_in[2];
  const float* wxi = (const float*)d_in[3];
  const float* wxj = (const float*)d_in[4];
  const float* wxk = (const float*)d_in[5];
  const float* wxb = (const float*)d_in[6];
  const float* uhr = (const float*)d_in[7];
  const float* uhi = (const float*)d_in[8];
  const float* uhj = (const float*)d_in[9];
  const float* uhk = (const float*)d_in[10];
  const float* uhb = (const float*)d_in[11];
  float* out = (float*)d_out;

  constexpr size_t HH = (size_t)H_DIM * H_DIM;   // 1M elems
  char* ws = (char*)d_ws;
  size_t off = 0;
  auto take = [&](size_t bytes) { void* p = ws + off; off += (bytes + 255) & ~(size_t)255; return p; };
  unsigned short* Bstack = (unsigned short*)take(JT * HH * 2);       // (W^1..W^8)^T, 16 MB
  unsigned short* Wrow   = (unsigned short*)take(HH * 2);
  unsigned short* WwxT   = (unsigned short*)take((size_t)H_DIM * F_IN * 2);
  float*          bias   = (float*)take(H_DIM * 4);
  unsigned short* P2row  = (unsigned short*)take(HH * 2);
  unsigned short* P34row = (unsigned short*)take(2 * HH * 2);        // [1024][2048]
  unsigned short* P58row = (unsigned short*)take(4 * HH * 2);        // [1024][4096]
  unsigned short* P16T   = (unsigned short*)take(HH * 2);
  // Eext: 259 chunk-blocks. Eext[i] = E[i-3]; E[m]=Lend_m (m>=0), E[-1]=h0, E[<-1]=0.
  unsigned short* Eext   = (unsigned short*)take((size_t)(NCHUNK + 3) * BLK * 2);
  // S padded +BATCH rows: unmasked M=8192 S-fix writes spill into padding.
  unsigned short* S      = (unsigned short*)take((size_t)(SROWS + BATCH) * H_DIM * 2);
  // UL: bf16 [c*32+b][j*1024+col]; U written by gemm_u, overwritten by L in pass A.
  unsigned short* UL     = (unsigned short*)take((size_t)SROWS * ULW * 2);  // 128 MB
  if (off > ws_size) return;  // workspace too small; fail visibly

  build_wuh<<<dim3(HH / 256), 256, 0, stream>>>(uhr, uhi, uhj, uhk, Bstack, Wrow);
  build_wwx<<<dim3((H_DIM * F_IN) / 256), 256, 0, stream>>>(wxr, wxi, wxj, wxk, WwxT);
  build_bias<<<dim3(4), 256, 0, stream>>>(wxb, uhb, bias);

  // U = x @ W_wx + (wx_b + uh_b) -> UL bf16, qsplit layout
  gemm2<true, 128, 128><<<dim3(T_LEN * BATCH / 128, H_DIM / 128), 256, 0, stream>>>(
      x, F_IN, WwxT, T_LEN * BATCH, H_DIM, F_IN,
      bias, nullptr, 0, UL, ULW, 1, nullptr, nullptr);

  // Matrix powers (log-doubling); Bstack block m-1 = (W^m)^T.
  gemm2<false, 64, 128><<<dim3(16, 8), 256, 0, stream>>>(        // P2 = W@W
      Wrow, 1024, Bstack, 1024, 1024, 1024,
      nullptr, nullptr, 0, P2row, 1024, 0, nullptr, Bstack + 1 * HH);
  gemm2<false, 64, 128><<<dim3(16, 16), 256, 0, stream>>>(       // [P3,P4] = P2@[P1,P2]
      P2row, 1024, Bstack, 1024, 2048, 1024,
      nullptr, nullptr, 0, P34row, 2048, 0, nullptr, Bstack + 2 * HH);
  gemm2<false, 64, 128><<<dim3(16, 32), 256, 0, stream>>>(       // [P5..P8] = P4@[P1..P4]
      P34row + 1024, 2048, Bstack, 1024, 4096, 1024,
      nullptr, nullptr, 0, P58row, 4096, 0, nullptr, Bstack + 4 * HH);
  gemm2<false, 64, 128><<<dim3(16, 8), 256, 0, stream>>>(        // P16 = P8@P8
      P58row + 3 * 1024, 4096, Bstack + 7 * HH, 1024, 1024, 1024,
      nullptr, nullptr, 0, nullptr, 0, 0, nullptr, P16T);

  // Guard blocks + s_0
  hipMemsetAsync(Eext, 0, 2 * (size_t)BLK * 2, stream);             // E[-3], E[-2] = 0
  gather_bf16<<<dim3(BATCH), 256, 0, stream>>>(Eext + 2 * (size_t)BLK, h0); // E[-1]=h0
  gather_bf16<<<dim3(BATCH), 256, 0, stream>>>(S, h0);              // s_0 = h0

  // Pass A: L_j = L_{j-1}@W + U_j, all in UL col-blocks (bf16 only, gemmA).
  for (int j = 1; j < KC; ++j) {
    unsigned short* soC = (j == KC - 1) ? (Eext + 3 * (size_t)BLK) : nullptr; // Lend->Eext
    gemmA<<<dim3(SROWS / 128, H_DIM / 128), 256, 0, stream>>>(
        UL + (size_t)(j - 1) * H_DIM, ULW, Bstack, H_DIM,
        UL + (size_t)j * H_DIM, ULW,
        UL + (size_t)j * H_DIM, ULW, soC);
  }

  // S-fix (3-tap, unmasked M=8192; 32 extra rows land in S padding):
  // S[c] = E[c-1] + E[c-2]@W^8 + E[c-3]@W^16, c = 1..255
  gemmA<<<dim3(SROWS / 128, H_DIM / 128), 256, 0, stream>>>(
      Eext + 2 * (size_t)BLK, 1024, Bstack + 7 * HH, H_DIM,
      Eext + 3 * (size_t)BLK, 1024, S + (size_t)BLK, 1024, nullptr);
  gemmA<<<dim3(SROWS / 128, H_DIM / 128), 256, 0, stream>>>(
      Eext + 1 * (size_t)BLK, 1024, P16T, H_DIM,
      S + (size_t)BLK, 1024, S + (size_t)BLK, 1024, nullptr);

  // Corrections + final assembly: out[c*8+jm] = UL[c][jm] + S[c] @ W^{jm+1}
  gemm256<<<dim3(SROWS / 256, ULW / 256), 512, 0, stream>>>(
      S, Bstack, UL, out, H_DIM, KC * BATCH);

  copy_hlast<<<dim3(BATCH), 256, 0, stream>>>(out);
}

// Round 14
// 616.779 us; speedup vs baseline: 2.3122x; 1.2860x over previous
//
#include <hip/hip_runtime.h>

typedef __attribute__((ext_vector_type(8))) short short8;
typedef __attribute__((ext_vector_type(4))) short short4v;
typedef __attribute__((ext_vector_type(4))) float f32x4;

#define DEV __device__ __forceinline__

constexpr int T_LEN  = 2048;
constexpr int BATCH  = 32;
constexpr int F_IN   = 64;
constexpr int H_DIM  = 1024;
constexpr int HQ     = 256;
constexpr int KC     = 8;                // timesteps per chunk
constexpr int NCHUNK = T_LEN / KC;       // 256
constexpr int SROWS  = NCHUNK * BATCH;   // 8192 state rows
constexpr int JT     = 8;                // correction taps (W^1..W^8)
constexpr int BLK    = BATCH * H_DIM;    // elems per chunk-block (32x1024)
constexpr int ULW    = JT * H_DIM;       // UL row width = 8192

DEV unsigned short f2bf(float f) {
  union { float f; unsigned u; } v; v.f = f;
  return (unsigned short)((v.u + 0x7fffu + ((v.u >> 16) & 1u)) >> 16);
}
DEV float bf2f(unsigned short s) {
  union { unsigned u; float f; } v; v.u = ((unsigned)s) << 16;
  return v.f;
}

DEV void gload16(const unsigned short* src, unsigned short* ldsDst) {
  __builtin_amdgcn_global_load_lds(
      (const __attribute__((address_space(1))) void*)src,
      (__attribute__((address_space(3))) void*)ldsDst, 16, 0, 0);
}

// Build W_uh as W^T (row-major [n][k] -> Bstack block 0) and W row-major.
__global__ void build_wuh(const float* __restrict__ cr, const float* __restrict__ ci,
                          const float* __restrict__ cj, const float* __restrict__ ck,
                          unsigned short* __restrict__ WT, unsigned short* __restrict__ Wrow) {
  int id = blockIdx.x * 256 + threadIdx.x;   // id = n*1024 + k
  int n = id >> 10, k = id & 1023;
  int q = n >> 8, b = n & 255, p = k >> 8, a = k & 255;
  const float* comps[4] = {cr, ci, cj, ck};
  const int   csel[16] = {0,1,2,3, 1,0,3,2, 2,3,0,1, 3,2,1,0};
  const float csgn[16] = {1.f,-1.f,-1.f,-1.f, 1.f,1.f,-1.f,1.f,
                          1.f,1.f,1.f,-1.f, 1.f,-1.f,1.f,1.f};
  float v = csgn[q*4+p] * comps[csel[q*4+p]][a*HQ + b];
  unsigned short bv = f2bf(v);
  WT[(size_t)n * 1024 + k] = bv;
  Wrow[(size_t)k * 1024 + n] = bv;
}

// Build W_wx^T (bf16, [n=1024][k=64]).
__global__ void build_wwx(const float* __restrict__ cr, const float* __restrict__ ci,
                          const float* __restrict__ cj, const float* __restrict__ ck,
                          unsigned short* __restrict__ WT) {
  int id = blockIdx.x * 256 + threadIdx.x;   // id = n*64 + k
  int n = id >> 6, k = id & 63;
  int q = n >> 8, b = n & 255, p = k >> 4, a = k & 15;
  const float* comps[4] = {cr, ci, cj, ck};
  const int   csel[16] = {0,1,2,3, 1,0,3,2, 2,3,0,1, 3,2,1,0};
  const float csgn[16] = {1.f,-1.f,-1.f,-1.f, 1.f,1.f,-1.f,1.f,
                          1.f,1.f,1.f,-1.f, 1.f,-1.f,1.f,1.f};
  float v = csgn[q*4+p] * comps[csel[q*4+p]][a*HQ + b];
  WT[(size_t)n * 64 + k] = f2bf(v);
}

__global__ void build_bias(const float* __restrict__ a, const float* __restrict__ b,
                           float* __restrict__ o) {
  int i = blockIdx.x * 256 + threadIdx.x;
  if (i < H_DIM) o[i] = a[i] + b[i];
}

// Gather fp32 rows -> contiguous bf16 rows (h0 staging).
__global__ void gather_bf16(unsigned short* __restrict__ dst, const float* __restrict__ src) {
  int r = blockIdx.x, tid = threadIdx.x;
  const float4* s = (const float4*)(src + (size_t)r * H_DIM);
  float4 v = s[tid];
  short4v o;
  o[0] = (short)f2bf(v.x); o[1] = (short)f2bf(v.y);
  o[2] = (short)f2bf(v.z); o[3] = (short)f2bf(v.w);
  *(short4v*)(dst + (size_t)r * H_DIM + tid * 4) = o;
}

__global__ void copy_hlast(float* __restrict__ out) {
  int b = blockIdx.x, tid = threadIdx.x;
  const float4* s = (const float4*)(out + ((size_t)(T_LEN - 1) * BATCH + b) * H_DIM);
  float4* d = (float4*)(out + (size_t)T_LEN * BATCH * H_DIM + (size_t)b * H_DIM);
  d[tid] = s[tid];
}

// ---------------- r4-proven GEMM engine (gemm_u + powers only) ----------------
template<bool AF32, int BM, int BN>
__launch_bounds__(256)
__global__ void gemm2(const void* __restrict__ Ap, int lda,
                      const unsigned short* __restrict__ Bt,
                      int M, int N, int K,
                      const float* __restrict__ bias,
                      const unsigned short* __restrict__ addBF, int strideBF,
                      unsigned short* __restrict__ stateOut, int strideS, int smode,
                      unsigned short* __restrict__ stateOutC,
                      unsigned short* __restrict__ stateOutT) {
  constexpr int TM = BM / 2, TN = BN / 2;    // 2x2 waves
  constexpr int FM = TM / 16, FN = TN / 16;
  __shared__ __align__(16) unsigned short Al[BM * 32];
  __shared__ __align__(16) unsigned short Bl[BN * 32];

  const int tid = threadIdx.x;
  const int lane = tid & 63, w = tid >> 6;
  const int bm0 = blockIdx.x * BM, bn0 = blockIdx.y * BN;
  const int wm = (w >> 1) * TM, wn = (w & 1) * TN;
  const int lr = lane & 15, lk = (lane >> 4) * 8;

  f32x4 acc[FM][FN];
#pragma unroll
  for (int i = 0; i < FM; ++i)
#pragma unroll
    for (int j = 0; j < FN; ++j)
#pragma unroll
      for (int q = 0; q < 4; ++q) acc[i][j][q] = 0.f;

  for (int kt = 0; kt < K; kt += 32) {
    if constexpr (AF32) {
#pragma unroll
      for (int ch = 0; ch < BM / 64; ++ch) {
        int c = ch * 256 + tid;
        int row = c >> 2, kp = (c & 3) * 8;
        int gr = bm0 + row;
        short8 v;
#pragma unroll
        for (int e = 0; e < 8; ++e) v[e] = 0;
        if (gr < M) {
          const float* a = (const float*)Ap + (size_t)gr * lda + kt + kp;
          float4 x0 = *(const float4*)a;
          float4 x1 = *(const float4*)(a + 4);
          v[0] = (short)f2bf(x0.x); v[1] = (short)f2bf(x0.y);
          v[2] = (short)f2bf(x0.z); v[3] = (short)f2bf(x0.w);
          v[4] = (short)f2bf(x1.x); v[5] = (short)f2bf(x1.y);
          v[6] = (short)f2bf(x1.z); v[7] = (short)f2bf(x1.w);
        }
        *(short8*)&Al[c * 8] = v;
      }
    } else {
#pragma unroll
      for (int ch = 0; ch < BM / 64; ++ch) {
        int c = ch * 256 + tid;
        int row = c >> 2, kp = (c & 3) * 8;
        int gr = bm0 + row;
        if (gr >= M) gr = M - 1;   // clamp: safe load, output masked later
        const unsigned short* src = (const unsigned short*)Ap + (size_t)gr * lda + kt + kp;
        gload16(src, &Al[c * 8]);
      }
    }
#pragma unroll
    for (int ch = 0; ch < BN / 64; ++ch) {
      int c = ch * 256 + tid;
      int row = c >> 2, kp = (c & 3) * 8;
      const unsigned short* src = Bt + (size_t)(bn0 + row) * K + kt + kp;
      gload16(src, &Bl[c * 8]);
    }
    __syncthreads();
    short8 af[FM], bfr[FN];
#pragma unroll
    for (int i = 0; i < FM; ++i) af[i] = *(const short8*)&Al[(wm + i * 16 + lr) * 32 + lk];
#pragma unroll
    for (int j = 0; j < FN; ++j) bfr[j] = *(const short8*)&Bl[(wn + j * 16 + lr) * 32 + lk];
#pragma unroll
    for (int i = 0; i < FM; ++i)
#pragma unroll
      for (int j = 0; j < FN; ++j)
        acc[i][j] = __builtin_amdgcn_mfma_f32_16x16x32_bf16(af[i], bfr[j], acc[i][j], 0, 0, 0);
    __syncthreads();
  }

#pragma unroll
  for (int i = 0; i < FM; ++i) {
    const int r0 = bm0 + wm + i * 16 + (lane >> 4) * 4;
#pragma unroll
    for (int j = 0; j < FN; ++j) {
      const int n = bn0 + wn + j * 16 + (lane & 15);
      short4v tv;
#pragma unroll
      for (int q = 0; q < 4; ++q) {
        int r = r0 + q;
        if (r >= M) continue;
        float v = acc[i][j][q];
        if (bias) v += bias[n];
        if (addBF) v += bf2f(addBF[(size_t)r * strideBF + n]);
        unsigned short bv = f2bf(v);
        if (stateOut) {
          if (smode == 0) {
            stateOut[(size_t)r * strideS + n] = bv;
          } else {
            int srow = (r >> 8) * 32 + (r & 31);
            int scol = ((r >> 5) & 7) * H_DIM + n;
            stateOut[(size_t)srow * strideS + scol] = bv;
          }
        }
        if (stateOutC) stateOutC[(size_t)r * N + n] = bv;
        tv[q] = (short)bv;
      }
      if (stateOutT && r0 < M)
        *(short4v*)(stateOutT + (size_t)n * M + r0) = tv;
    }
  }
}

// --------- 128x128 / BK=64 counted-vmcnt GEMM (pass A + merged S-fix) ---------
// K-loop/barrier skeleton = r13 (verified). r14: (a) LDS-staged vectorized
// epilogue (acc -> LDS fp32 -> short8 coalesced RMW); (b) banded-A / dual-B
// support: for k<1024 A row += band and B=B0, else B=B1 (merged 2-tap S-fix).
__launch_bounds__(256)
__global__ void gemmA(const unsigned short* __restrict__ A, int lda,
                      const unsigned short* __restrict__ B0,
                      const unsigned short* __restrict__ B1,
                      int Ksize, int band,
                      const unsigned short* __restrict__ addBF, int strideBF,
                      unsigned short* __restrict__ stateOut, int strideS,
                      unsigned short* __restrict__ stateOutC) {
  __shared__ __align__(16) unsigned char smem[65536];
  unsigned short* As = (unsigned short*)smem;            // [2][128][64] bf16
  unsigned short* Bs = (unsigned short*)(smem + 32768);  // [2][128][64] bf16

  const int tid = threadIdx.x;
  const int lane = tid & 63, w = tid >> 6;
  const int wm = w >> 1, wn = w & 1;          // 2x2 wave grid
  const int lr = lane & 15, hi = lane >> 4;
  const int bm0 = blockIdx.x * 128, bn0 = blockIdx.y * 128;

  f32x4 acc[4][4];
#pragma unroll
  for (int i = 0; i < 4; ++i)
#pragma unroll
    for (int j = 0; j < 4; ++j)
#pragma unroll
      for (int q = 0; q < 4; ++q) acc[i][j][q] = 0.f;

  auto stageTile = [&](int b, int t) {
    const int kt = t * 64;
    const int kc = kt & 1023;
    const int roff = (kt < 1024) ? band : 0;
    const unsigned short* Bsel = (kt < 1024) ? B0 : B1;
#pragma unroll
    for (int li = 0; li < 4; ++li) {
      int s = li * 256 + tid;                  // 0..1023 slots of 16B
      int row = s >> 3, c16 = s & 7;
      gload16(A + (size_t)(bm0 + row + roff) * lda + kc + ((c16 ^ (row & 7)) << 3),
              &As[(b * 128 + row) * 64 + c16 * 8]);
    }
#pragma unroll
    for (int li = 0; li < 4; ++li) {
      int s = li * 256 + tid;
      int row = s >> 3, c16 = s & 7;
      gload16(Bsel + (size_t)(bn0 + row) * 1024 + kc + ((c16 ^ (row & 7)) << 3),
              &Bs[(b * 128 + row) * 64 + c16 * 8]);
    }
  };

  const int NT = Ksize / 64;
  stageTile(0, 0);
  stageTile(1, 1);
  asm volatile("s_waitcnt vmcnt(8)" ::: "memory");   // tile 0 landed; tile 1 in flight
  __builtin_amdgcn_s_barrier();
  asm volatile("" ::: "memory");
  __builtin_amdgcn_sched_barrier(0);

  for (int t = 0; t < NT; ++t) {
    const int b = t & 1;
    short8 af[2][4], bw[2][4];
#pragma unroll
    for (int kk = 0; kk < 2; ++kk) {
      const int c16k = (kk << 2) + hi;
#pragma unroll
      for (int mf = 0; mf < 4; ++mf) {
        int rl = wm * 64 + mf * 16 + lr;
        af[kk][mf] = *(const short8*)&As[(b * 128 + rl) * 64 + (c16k ^ (lr & 7)) * 8];
      }
#pragma unroll
      for (int nf = 0; nf < 4; ++nf) {
        int rn = wn * 64 + nf * 16 + lr;
        bw[kk][nf] = *(const short8*)&Bs[(b * 128 + rn) * 64 + (c16k ^ (lr & 7)) * 8];
      }
    }
    __builtin_amdgcn_s_setprio(1);
#pragma unroll
    for (int mf = 0; mf < 4; ++mf)
#pragma unroll
      for (int nf = 0; nf < 4; ++nf)
#pragma unroll
        for (int kk = 0; kk < 2; ++kk)
          acc[mf][nf] = __builtin_amdgcn_mfma_f32_16x16x32_bf16(
              af[kk][mf], bw[kk][nf], acc[mf][nf], 0, 0, 0);
    __builtin_amdgcn_s_setprio(0);
    asm volatile("" ::: "memory");
    __builtin_amdgcn_s_barrier();              // all waves done reading buf b
    asm volatile("" ::: "memory");
    if (t + 2 < NT) {
      stageTile(b, t + 2);
      asm volatile("s_waitcnt vmcnt(8)" ::: "memory"); // t+1 landed; t+2 in flight
    } else {
      asm volatile("s_waitcnt vmcnt(0)" ::: "memory"); // tail drain
    }
    __builtin_amdgcn_s_barrier();
    asm volatile("" ::: "memory");
    __builtin_amdgcn_sched_barrier(0);
  }

  // ---- vectorized epilogue: acc -> LDS fp32 [128][128] -> short8 RMW ----
  float* Cs = (float*)smem;                    // 64 KB exactly
  __syncthreads();                             // K-loop reads fully done
#pragma unroll
  for (int mf = 0; mf < 4; ++mf)
#pragma unroll
    for (int nf = 0; nf < 4; ++nf)
#pragma unroll
      for (int q = 0; q < 4; ++q) {
        int row = wm * 64 + mf * 16 + hi * 4 + q;
        int col = wn * 64 + nf * 16 + lr;
        Cs[row * 128 + col] = acc[mf][nf][q];
      }
  __syncthreads();
#pragma unroll
  for (int it = 0; it < 8; ++it) {
    int slot = it * 256 + tid;                 // 128 rows x 16 col8-slots
    int row = slot >> 4, c8 = (slot & 15) * 8;
    int r = bm0 + row, n = bn0 + c8;
    const float* cp = &Cs[row * 128 + c8];
    short8 ul, outv;
    if (addBF) ul = *(const short8*)&addBF[(size_t)r * strideBF + n];
#pragma unroll
    for (int e = 0; e < 8; ++e) {
      float v = cp[e];
      if (addBF) v += bf2f((unsigned short)ul[e]);
      outv[e] = (short)f2bf(v);
    }
    *(short8*)&stateOut[(size_t)r * strideS + n] = outv;
    if (stateOutC) *(short8*)&stateOutC[(size_t)r * H_DIM + n] = outv;
  }
}

// ------------- 256x256 / BK=64 phase-structured GEMM (corr only) -------------
// K-loop skeleton = r13 (verified). r14: LDS-staged vectorized epilogue
// (two 128-row passes; float4 out stores + short4 UL loads, fully coalesced).
__launch_bounds__(512)
__global__ void gemm256(const unsigned short* __restrict__ A,
                        const unsigned short* __restrict__ Bt,
                        const unsigned short* __restrict__ addBF,
                        float* __restrict__ outF,
                        int K, int mapStride) {
  __shared__ __align__(16) unsigned char smem[131072];
  unsigned short* As = (unsigned short*)smem;            // [2][2][128][64]
  unsigned short* Bs = (unsigned short*)(smem + 65536);  // [2][2][128][64]

  const int tid = threadIdx.x;
  const int lane = tid & 63, w = tid >> 6;
  const int wm = w >> 2, wn = w & 3;          // 2x4 wave grid
  const int lr = lane & 15, hi = lane >> 4;
  const int bm0 = blockIdx.x * 256, bn0 = blockIdx.y * 256;

  f32x4 acc[8][4];
#pragma unroll
  for (int i = 0; i < 8; ++i)
#pragma unroll
    for (int j = 0; j < 4; ++j)
#pragma unroll
      for (int q = 0; q < 4; ++q) acc[i][j][q] = 0.f;

  auto stageTile = [&](int b, int t) {
    const int kt = t * 64;
#pragma unroll
    for (int h = 0; h < 2; ++h)
#pragma unroll
      for (int li = 0; li < 2; ++li) {
        int s = li * 512 + tid;              // 0..1023 slots of 16B
        int row = s >> 3, c16 = s & 7;
        gload16(A + (size_t)(bm0 + h * 128 + row) * K + kt + ((c16 ^ (row & 7)) << 3),
                &As[((b * 2 + h) * 128 + row) * 64 + c16 * 8]);
      }
#pragma unroll
    for (int h = 0; h < 2; ++h)
#pragma unroll
      for (int li = 0; li < 2; ++li) {
        int s = li * 512 + tid;
        int row = s >> 3, c16 = s & 7;
        gload16(Bt + (size_t)(bn0 + h * 128 + row) * K + kt + ((c16 ^ (row & 7)) << 3),
                &Bs[((b * 2 + h) * 128 + row) * 64 + c16 * 8]);
      }
  };

  const int NT = K / 64;                       // 16
  stageTile(0, 0);
  stageTile(1, 1);
  asm volatile("s_waitcnt vmcnt(8)" ::: "memory");   // tile 0 landed; tile 1 in flight
  __builtin_amdgcn_s_barrier();
  asm volatile("" ::: "memory");
  __builtin_amdgcn_sched_barrier(0);

  for (int t = 0; t < NT; ++t) {
    const int b = t & 1;
#pragma unroll
    for (int kk = 0; kk < 2; ++kk) {
      const int c16k = (kk << 2) + hi;
      short8 af[8], bw[4];
#pragma unroll
      for (int m = 0; m < 8; ++m)
        af[m] = *(const short8*)&As[((b * 2 + wm) * 128 + m * 16 + lr) * 64 +
                                    (c16k ^ (lr & 7)) * 8];
#pragma unroll
      for (int n2 = 0; n2 < 4; ++n2)
        bw[n2] = *(const short8*)&Bs[((b * 2 + (wn >> 1)) * 128 +
                                      (wn & 1) * 64 + n2 * 16 + lr) * 64 +
                                     (c16k ^ (lr & 7)) * 8];
      __builtin_amdgcn_s_setprio(1);
#pragma unroll
      for (int m = 0; m < 8; ++m)
#pragma unroll
        for (int n2 = 0; n2 < 4; ++n2)
          acc[m][n2] = __builtin_amdgcn_mfma_f32_16x16x32_bf16(
              af[m], bw[n2], acc[m][n2], 0, 0, 0);
      __builtin_amdgcn_s_setprio(0);
    }
    asm volatile("" ::: "memory");
    __builtin_amdgcn_s_barrier();
    asm volatile("" ::: "memory");
    if (t + 2 < NT) {
      stageTile(b, t + 2);
      asm volatile("s_waitcnt vmcnt(8)" ::: "memory"); // t+1 landed; t+2 stays in flight
    } else {
      asm volatile("s_waitcnt vmcnt(0)" ::: "memory"); // tail drain
    }
    __builtin_amdgcn_s_barrier();
    asm volatile("" ::: "memory");
    __builtin_amdgcn_sched_barrier(0);
  }

  // ---- vectorized epilogue: two passes of 128 rows staged in LDS fp32 ----
  float* Cs = (float*)smem;                    // [128][256] fp32 = 128 KB
#pragma unroll
  for (int P = 0; P < 2; ++P) {
    __syncthreads();
    if (wm == P) {
#pragma unroll
      for (int i = 0; i < 8; ++i)
#pragma unroll
        for (int j = 0; j < 4; ++j)
#pragma unroll
          for (int q = 0; q < 4; ++q) {
            int row = i * 16 + hi * 4 + q;     // 0..127
            int col = wn * 64 + j * 16 + lr;   // 0..255
            Cs[row * 256 + col] = acc[i][j][q];
          }
    }
    __syncthreads();
#pragma unroll
    for (int it = 0; it < 16; ++it) {
      int slot = it * 512 + tid;               // 128 rows x 64 col4-slots
      int row = slot >> 6, c4 = (slot & 63) * 4;
      int r = bm0 + P * 128 + row, n = bn0 + c4;
      int col = n & 1023, jm = n >> 10;
      int g = (r >> 5) * mapStride + jm * BATCH + (r & 31);
      const float* cp = &Cs[row * 256 + c4];
      short4v ul = *(const short4v*)&addBF[(size_t)r * ULW + n];
      float4 res;
      res.x = cp[0] + bf2f((unsigned short)ul[0]);
      res.y = cp[1] + bf2f((unsigned short)ul[1]);
      res.z = cp[2] + bf2f((unsigned short)ul[2]);
      res.w = cp[3] + bf2f((unsigned short)ul[3]);
      *(float4*)&outF[(size_t)g * H_DIM + col] = res;
    }
  }
}

extern "C" void kernel_launch(void* const* d_in, const int* in_sizes, int n_in,
                              void* d_out, int out_size, void* d_ws, size_t ws_size,
                              hipStream_t stream) {
  const float* x   = (const float*)d_in[0];
  const float* h0  = (const float*)d_in[1];
  const float* wxr = (const float*)d_in[2];
  const float* wxi = (const float*)d_in[3];
  const float* wxj = (const float*)d_in[4];
  const float* wxk = (const float*)d_in[5];
  const float* wxb = (const float*)d_in[6];
  const float* uhr = (const float*)d_in[7];
  const float* uhi = (const float*)d_in[8];
  const float* uhj = (const float*)d_in[9];
  const float* uhk = (const float*)d_in[10];
  const float* uhb = (const float*)d_in[11];
  float* out = (float*)d_out;

  constexpr size_t HH = (size_t)H_DIM * H_DIM;   // 1M elems
  char* ws = (char*)d_ws;
  size_t off = 0;
  auto take = [&](size_t bytes) { void* p = ws + off; off += (bytes + 255) & ~(size_t)255; return p; };
  unsigned short* Bstack = (unsigned short*)take(JT * HH * 2);       // (W^1..W^8)^T, 16 MB
  unsigned short* Wrow   = (unsigned short*)take(HH * 2);
  unsigned short* WwxT   = (unsigned short*)take((size_t)H_DIM * F_IN * 2);
  float*          bias   = (float*)take(H_DIM * 4);
  unsigned short* P2row  = (unsigned short*)take(HH * 2);
  unsigned short* P34row = (unsigned short*)take(2 * HH * 2);        // [1024][2048]
  unsigned short* P58row = (unsigned short*)take(4 * HH * 2);        // [1024][4096]
  unsigned short* P16T   = (unsigned short*)take(HH * 2);
  // Eext: 259 chunk-blocks. Eext[i] = E[i-3]; E[m]=Lend_m (m>=0), E[-1]=h0, E[<-1]=0.
  unsigned short* Eext   = (unsigned short*)take((size_t)(NCHUNK + 3) * BLK * 2);
  // S padded +BATCH rows: unmasked M=8192 S-fix writes spill into padding.
  unsigned short* S      = (unsigned short*)take((size_t)(SROWS + BATCH) * H_DIM * 2);
  // UL: bf16 [c*32+b][j*1024+col]; U written by gemm_u, overwritten by L in pass A.
  unsigned short* UL     = (unsigned short*)take((size_t)SROWS * ULW * 2);  // 128 MB
  if (off > ws_size) return;  // workspace too small; fail visibly

  build_wuh<<<dim3(HH / 256), 256, 0, stream>>>(uhr, uhi, uhj, uhk, Bstack, Wrow);
  build_wwx<<<dim3((H_DIM * F_IN) / 256), 256, 0, stream>>>(wxr, wxi, wxj, wxk, WwxT);
  build_bias<<<dim3(4), 256, 0, stream>>>(wxb, uhb, bias);

  // U = x @ W_wx + (wx_b + uh_b) -> UL bf16, qsplit layout
  gemm2<true, 128, 128><<<dim3(T_LEN * BATCH / 128, H_DIM / 128), 256, 0, stream>>>(
      x, F_IN, WwxT, T_LEN * BATCH, H_DIM, F_IN,
      bias, nullptr, 0, UL, ULW, 1, nullptr, nullptr);

  // Matrix powers (log-doubling); Bstack block m-1 = (W^m)^T.
  gemm2<false, 64, 128><<<dim3(16, 8), 256, 0, stream>>>(        // P2 = W@W
      Wrow, 1024, Bstack, 1024, 1024, 1024,
      nullptr, nullptr, 0, P2row, 1024, 0, nullptr, Bstack + 1 * HH);
  gemm2<false, 64, 128><<<dim3(16, 16), 256, 0, stream>>>(       // [P3,P4] = P2@[P1,P2]
      P2row, 1024, Bstack, 1024, 2048, 1024,
      nullptr, nullptr, 0, P34row, 2048, 0, nullptr, Bstack + 2 * HH);
  gemm2<false, 64, 128><<<dim3(16, 32), 256, 0, stream>>>(       // [P5..P8] = P4@[P1..P4]
      P34row + 1024, 2048, Bstack, 1024, 4096, 1024,
      nullptr, nullptr, 0, P58row, 4096, 0, nullptr, Bstack + 4 * HH);
  gemm2<false, 64, 128><<<dim3(16, 8), 256, 0, stream>>>(        // P16 = P8@P8
      P58row + 3 * 1024, 4096, Bstack + 7 * HH, 1024, 1024, 1024,
      nullptr, nullptr, 0, nullptr, 0, 0, nullptr, P16T);

  // Guard blocks + s_0
  hipMemsetAsync(Eext, 0, 2 * (size_t)BLK * 2, stream);             // E[-3], E[-2] = 0
  gather_bf16<<<dim3(BATCH), 256, 0, stream>>>(Eext + 2 * (size_t)BLK, h0); // E[-1]=h0
  gather_bf16<<<dim3(BATCH), 256, 0, stream>>>(S, h0);              // s_0 = h0

  // Pass A: L_j = L_{j-1}@W + U_j, all in UL col-blocks (bf16 only, gemmA).
  for (int j = 1; j < KC; ++j) {
    unsigned short* soC = (j == KC - 1) ? (Eext + 3 * (size_t)BLK) : nullptr; // Lend->Eext
    gemmA<<<dim3(SROWS / 128, H_DIM / 128), 256, 0, stream>>>(
        UL + (size_t)(j - 1) * H_DIM, ULW, Bstack, Bstack, 1024, 0,
        UL + (size_t)j * H_DIM, ULW,
        UL + (size_t)j * H_DIM, ULW, soC);
  }

  // S-fix (3-tap, merged banded K=2048, unmasked M=8192; spill rows -> S pad):
  // S[c] = E[c-1] + E[c-2]@W^8 + E[c-3]@W^16, c = 1..255
  // k<1024: A row r+32 from base (E[c-2]) with B0=W^8; k>=1024: row r (E[c-3]) B1=W^16.
  gemmA<<<dim3(SROWS / 128, H_DIM / 128), 256, 0, stream>>>(
      Eext + 1 * (size_t)BLK, 1024, Bstack + 7 * HH, P16T, 2048, 32,
      Eext + 3 * (size_t)BLK, 1024,
      S + (size_t)BLK, 1024, nullptr);

  // Corrections + final assembly: out[c*8+jm] = UL[c][jm] + S[c] @ W^{jm+1}
  gemm256<<<dim3(SROWS / 256, ULW / 256), 512, 0, stream>>>(
      S, Bstack, UL, out, H_DIM, KC * BATCH);

  copy_hlast<<<dim3(BATCH), 256, 0, stream>>>(out);
}